// Round 14
// baseline (780.169 us; speedup 1.0000x reference)
//
#include <hip/hip_runtime.h>
#include <math.h>

#define T_TOK 8192
#define HDIM 2048
#define IDIM 1024
#define NE 8

typedef __attribute__((ext_vector_type(8))) short short8;
typedef __attribute__((ext_vector_type(4))) float f32x4;
typedef unsigned short u16;

__device__ inline u16 f2bf(float f) {
  unsigned u = __builtin_bit_cast(unsigned, f);
  u += 0x7fffu + ((u >> 16) & 1);  // RNE
  return (u16)(u >> 16);
}
__device__ inline float bf2f(u16 u) {
  unsigned v = (unsigned)u << 16;
  return __builtin_bit_cast(float, v);
}

// async global->LDS, 16B/lane. LDS dest = wave-uniform base + lane*16.
__device__ inline void gl_lds(const u16* g, u16* l) {
  __builtin_amdgcn_global_load_lds((const __attribute__((address_space(1))) unsigned int*)g,
                                   (__attribute__((address_space(3))) unsigned int*)l, 16, 0, 0);
}

// bf16 LDS tiles [row][32] (64B rows); chunk swizzle applied on the GLOBAL
// source address (m173): position p holds global chunk p ^ ((row>>1)&3).
// Frag read of granule g: row*32 + 8*(g ^ ((row>>1)&3)) -> 2-way banks (free).
__device__ inline int rswz(int row, int g) { return row * 32 + 8 * (g ^ ((row >> 1) & 3)); }

// local exclusive-prefix over cnt (replaces k2; 8 uniform L2-hot loads)
__device__ inline unsigned prefix_base(const unsigned* cnt, int e) {
  unsigned b = 0;
#pragma unroll
  for (int i = 0; i < NE; ++i) b += (i < e) ? cnt[i] : 0u;
  return b;
}

// ---------- ws layout ----------
// 0       meta: cnt[8] cursor[8] (u32; zeroed by memset)
// 256     slot_token u16[2T]  (32 KB)
// 33024   slot_w    f32[2T]   (64 KB)
// 98560   tok2slot  u16[2T]   (32 KB; kept for layout stability)
// 132096  xbf  bf16[T*H]      (33.5 MB)
// ACT     act  bf16[2T*I]     (33.5 MB)  (sel/wt stashed here pre-k4)
// WGT     wgT / wuT           (67 MB)
// WDT     wdT                 (33.5 MB)  total 167,904,256 (proven R5)

// ---------------- K01: router + x->bf16 + out-zero (x read ONCE) ----------------
__global__ __launch_bounds__(256) void k01_router_cvt(const float* __restrict__ x,
                                                      const float* __restrict__ wgate,
                                                      u16* __restrict__ xb,
                                                      float* __restrict__ out_zero,
                                                      float* __restrict__ logits_out,
                                                      char* __restrict__ sel,
                                                      float* __restrict__ wt,
                                                      unsigned* __restrict__ cnt) {
  // zero the combine target (k5 atomics accumulate into it)
  {
    size_t gid = (size_t)blockIdx.x * 256 + threadIdx.x;
    size_t n4 = (size_t)T_TOK * HDIM / 4;
    float4* o4 = (float4*)out_zero;
    float4 z = make_float4(0.f, 0.f, 0.f, 0.f);
    for (size_t p = gid; p < n4; p += (size_t)gridDim.x * 256) o4[p] = z;
  }
  int wave = threadIdx.x >> 6;
  int lane = threadIdx.x & 63;
  int t = blockIdx.x * 4 + wave;
  float acc[NE];
#pragma unroll
  for (int e = 0; e < NE; ++e) acc[e] = 0.f;
  const float4* xr = (const float4*)(x + (size_t)t * HDIM);
  u16* xbrow = xb + (size_t)t * HDIM;
#pragma unroll
  for (int c = 0; c < HDIM / 256; ++c) {
    float4 xv = xr[c * 64 + lane];
    int h = (c * 64 + lane) * 4;
    ushort4 o = make_ushort4(f2bf(xv.x), f2bf(xv.y), f2bf(xv.z), f2bf(xv.w));
    *(ushort4*)(xbrow + h) = o;
    const float xs[4] = {xv.x, xv.y, xv.z, xv.w};
#pragma unroll
    for (int j = 0; j < 4; ++j) {
      const float* wrow = wgate + (size_t)(h + j) * NE;
#pragma unroll
      for (int e = 0; e < NE; ++e) acc[e] += xs[j] * wrow[e];
    }
  }
#pragma unroll
  for (int e = 0; e < NE; ++e) {
    float v = acc[e];
#pragma unroll
    for (int off = 32; off; off >>= 1) v += __shfl_xor(v, off, 64);
    acc[e] = v;
  }
  if (lane == 0) {
    float m = acc[0];
#pragma unroll
    for (int e = 0; e < NE; ++e) {
      logits_out[(size_t)t * NE + e] = acc[e];
      m = fmaxf(m, acc[e]);
    }
    float p[NE];
#pragma unroll
    for (int e = 0; e < NE; ++e) p[e] = expf(acc[e] - m);
    int b0 = 0;
    float v0 = p[0];
#pragma unroll
    for (int e = 1; e < NE; ++e)
      if (p[e] > v0) { v0 = p[e]; b0 = e; }
    int b1 = -1;
    float v1 = -1.f;
#pragma unroll
    for (int e = 0; e < NE; ++e)
      if (e != b0 && p[e] > v1) { v1 = p[e]; b1 = e; }
    float denom = v0 + v1;
    sel[t * 2 + 0] = (char)b0;
    sel[t * 2 + 1] = (char)b1;
    wt[t * 2 + 0] = v0 / denom;
    wt[t * 2 + 1] = v1 / denom;
    atomicAdd(&cnt[b0], 1u);
    atomicAdd(&cnt[b1], 1u);
  }
}

// ---------------- KT: all three weight transposes, one launch ----------------
__global__ __launch_bounds__(256) void kt_all(const float* __restrict__ wg, u16* __restrict__ wgT,
                                              const float* __restrict__ wu, u16* __restrict__ wuT,
                                              const float* __restrict__ wd, u16* __restrict__ wdT) {
  __shared__ u16 t[64][72];
  unsigned bid = blockIdx.x;
  unsigned mat = bid / (512u * NE);  // 0=wg 1=wu 2=wd
  unsigned rem = bid % (512u * NE);
  unsigned e = rem / 512u;
  unsigned tile = rem % 512u;
  int K = (mat == 2) ? IDIM : HDIM;
  int N = (mat == 2) ? HDIM : IDIM;
  const float* src = (mat == 0 ? wg : mat == 1 ? wu : wd) + (size_t)e * K * N;
  u16* dst = (mat == 0 ? wgT : mat == 1 ? wuT : wdT) + (size_t)e * K * N;
  int ntiles_n = N / 64;
  int nb = (int)(tile % ntiles_n) * 64;
  int kb = (int)(tile / ntiles_n) * 64;

  int tid = threadIdx.x;
  int lk = tid >> 4, ln = (tid & 15) * 4;
#pragma unroll
  for (int p = 0; p < 4; ++p) {
    int k = lk + 16 * p;
    float4 v = *(const float4*)(src + (size_t)(kb + k) * N + nb + ln);
    t[ln + 0][k] = f2bf(v.x);
    t[ln + 1][k] = f2bf(v.y);
    t[ln + 2][k] = f2bf(v.z);
    t[ln + 3][k] = f2bf(v.w);
  }
  __syncthreads();
  int n = tid >> 2, c = tid & 3;
  short8 o0 = *(const short8*)&t[n][c * 16];
  short8 o1 = *(const short8*)&t[n][c * 16 + 8];
  u16* d = dst + (size_t)(nb + n) * K + kb + c * 16;
  *(short8*)d = o0;
  *(short8*)(d + 8) = o1;
}

// ---------------- K3: slot assignment (local prefix; cursor pre-zeroed) ----------------
__global__ __launch_bounds__(256) void k3_assign(const char* __restrict__ sel,
                                                 const float* __restrict__ wt,
                                                 const unsigned* __restrict__ cnt,
                                                 unsigned* __restrict__ cursor,
                                                 u16* __restrict__ slot_token,
                                                 float* __restrict__ slot_w) {
  unsigned offv[NE];
  unsigned s = 0;
#pragma unroll
  for (int e = 0; e < NE; ++e) {
    offv[e] = s;
    s += cnt[e];
  }
  int t = blockIdx.x * 256 + threadIdx.x;
#pragma unroll
  for (int k = 0; k < 2; ++k) {
    int e = sel[t * 2 + k];
    unsigned p = atomicAdd(&cursor[e], 1u);
    unsigned slot = offv[e] + p;
    slot_token[slot] = (u16)t;
    slot_w[slot] = wt[t * 2 + k];
  }
}

// Bijective XCD swizzles (8 XCDs).
__device__ inline void xcd_decomp32(int& bx, int& by, int& be) {  // 32x8x8 = 2048
  unsigned bid = blockIdx.x + 32u * (blockIdx.y + 8u * blockIdx.z);
  unsigned swz = (bid & 7u) * 256u + (bid >> 3);
  bx = swz & 31u;
  unsigned rem = swz >> 5;
  by = rem & 7u;
  be = rem >> 3;
}
__device__ inline void xcd_decomp64(int& bx, int& by, int& be) {  // 64x8x8 = 4096
  unsigned bid = blockIdx.x + 64u * (blockIdx.y + 8u * blockIdx.z);
  unsigned swz = (bid & 7u) * 512u + (bid >> 3);
  bx = swz & 63u;
  unsigned rem = swz >> 6;
  by = rem & 7u;
  be = rem >> 3;
}

// ---------------- K4: MFMA gate+up + silu -> bf16 act ----------------
// tile 256m x (128g+128u)n, 4 waves, WAVE tile 128m x (64g+64u)n:
// 16 b128 reads -> 64 MFMA per K-step (4.0 MFMA/read vs 2.67 in R9).
// Ring-3 LDS (96 KB), depth-2 prefetch, counted vmcnt (R9 schedule).
// acc 256 VGPR + operands -> needs (256,1); LDS-bound 1 block/CU.
__global__ __launch_bounds__(256, 1) void k4_gateup(
    const u16* __restrict__ xb, const u16* __restrict__ wgT, const u16* __restrict__ wuT,
    const u16* __restrict__ slot_token, const unsigned* __restrict__ cnt,
    u16* __restrict__ act) {
  int bx, by, e;
  xcd_decomp32(bx, by, e);
  unsigned n = cnt[e];
  unsigned row0 = (unsigned)bx * 256;
  if (row0 >= n) return;
  unsigned base = prefix_base(cnt, e);
  int col0 = by * 128;

  __shared__ __align__(16) u16 As[3][256 * 32];  // 48 KB
  __shared__ __align__(16) u16 Bg[3][128 * 32];  // 24 KB
  __shared__ __align__(16) u16 Bu[3][128 * 32];  // 24 KB

  int tid = threadIdx.x;
  int w = tid >> 6, l = tid & 63;
  int wr = w >> 1, wc = w & 1;
  int lr = l & 15, g = l >> 4;

  // A: 4 gl_lds/wave (16 rows each) covering rows 64w..64w+63
  const u16* asrc[4];
  int adst[4];
#pragma unroll
  for (int i = 0; i < 4; ++i) {
    int r = 64 * w + 16 * i + (l >> 2);
    unsigned grow = row0 + (unsigned)r;
    unsigned slot = base + (grow < n ? grow : 0);
    int chunk = (l & 3) ^ ((r >> 1) & 3);
    asrc[i] = xb + (size_t)slot_token[slot] * HDIM + 8 * chunk;
    adst[i] = (64 * w + 16 * i) * 32;
  }
  // B: 2 gl_lds/wave per matrix (n-rows 32w..32w+31)
  const u16* bgsrc[2];
  const u16* busrc[2];
  int bdst[2];
#pragma unroll
  for (int i = 0; i < 2; ++i) {
    int nn = 32 * w + 16 * i + (l >> 2);
    int chunk = (l & 3) ^ ((nn >> 1) & 3);
    size_t o = (size_t)e * HDIM * IDIM + (size_t)(col0 + nn) * HDIM + 8 * chunk;
    bgsrc[i] = wgT + o;
    busrc[i] = wuT + o;
    bdst[i] = (32 * w + 16 * i) * 32;
  }

  int afo[8], bfo[4];
#pragma unroll
  for (int mf = 0; mf < 8; ++mf) afo[mf] = rswz(wr * 128 + mf * 16 + lr, g);
#pragma unroll
  for (int nf = 0; nf < 4; ++nf) bfo[nf] = rswz(wc * 64 + nf * 16 + lr, g);

  f32x4 accg[8][4] = {};
  f32x4 accu[8][4] = {};

#define K4_STAGE(k0, buf)                           \
  do {                                              \
    gl_lds(asrc[0] + (k0), &As[buf][adst[0]]);      \
    gl_lds(asrc[1] + (k0), &As[buf][adst[1]]);      \
    gl_lds(asrc[2] + (k0), &As[buf][adst[2]]);      \
    gl_lds(asrc[3] + (k0), &As[buf][adst[3]]);      \
    gl_lds(bgsrc[0] + (k0), &Bg[buf][bdst[0]]);     \
    gl_lds(bgsrc[1] + (k0), &Bg[buf][bdst[1]]);     \
    gl_lds(busrc[0] + (k0), &Bu[buf][bdst[0]]);     \
    gl_lds(busrc[1] + (k0), &Bu[buf][bdst[1]]);     \
  } while (0)

  K4_STAGE(0, 0);
  K4_STAGE(32, 1);  // 16 loads in flight

  const int NK = HDIM / 32;
  int c = 0, sb = 2;
  for (int kt = 0; kt < NK; ++kt) {
    if (kt + 2 < NK) {
      K4_STAGE((kt + 2) * 32, sb);                       // 24 in flight
      asm volatile("s_waitcnt vmcnt(16)" ::: "memory");  // tile kt landed
    } else if (kt + 1 < NK) {
      asm volatile("s_waitcnt vmcnt(8)" ::: "memory");
    } else {
      asm volatile("s_waitcnt vmcnt(0)" ::: "memory");
    }
    __builtin_amdgcn_s_barrier();

    short8 af[8], bg[4], bu[4];
#pragma unroll
    for (int mf = 0; mf < 8; ++mf) af[mf] = *(const short8*)&As[c][afo[mf]];
#pragma unroll
    for (int nf = 0; nf < 4; ++nf) {
      bg[nf] = *(const short8*)&Bg[c][bfo[nf]];
      bu[nf] = *(const short8*)&Bu[c][bfo[nf]];
    }
#pragma unroll
    for (int nf = 0; nf < 4; ++nf)
#pragma unroll
      for (int mf = 0; mf < 8; ++mf) {
        accg[mf][nf] = __builtin_amdgcn_mfma_f32_16x16x32_bf16(af[mf], bg[nf], accg[mf][nf], 0, 0, 0);
        accu[mf][nf] = __builtin_amdgcn_mfma_f32_16x16x32_bf16(af[mf], bu[nf], accu[mf][nf], 0, 0, 0);
      }
    __builtin_amdgcn_s_barrier();
    c = (c == 2) ? 0 : c + 1;
    sb = (sb == 2) ? 0 : sb + 1;
  }
#undef K4_STAGE

  unsigned rows_left = n - row0;
#pragma unroll
  for (int mf = 0; mf < 8; ++mf)
#pragma unroll
    for (int nf = 0; nf < 4; ++nf)
#pragma unroll
      for (int j = 0; j < 4; ++j) {
        int rin = wr * 128 + mf * 16 + 4 * g + j;
        if ((unsigned)rin < rows_left) {
          size_t s = base + row0 + rin;
          int col = col0 + wc * 64 + nf * 16 + lr;
          float gg = accg[mf][nf][j];
          float uu = accu[mf][nf][j];
          float v = (gg / (1.f + expf(-gg))) * uu;
          act[s * IDIM + col] = f2bf(v);
        }
      }
}

// ---------------- K5: MFMA down + fused weighted combine (atomicAdd) ----------------
// tile 128m x 256n, 4 waves (64x128 each), BK=32, ring-3, depth-2, counted vmcnt.
// Epilogue: out[token] += w * acc (exactly 2 commutative fp32 adds/element).
__global__ __launch_bounds__(256, 2) void k5_down(
    const u16* __restrict__ act, const u16* __restrict__ wdT,
    const u16* __restrict__ slot_token, const float* __restrict__ slot_w,
    const unsigned* __restrict__ cnt, float* __restrict__ out) {
  int bx, by, e;
  xcd_decomp64(bx, by, e);
  unsigned n = cnt[e];
  unsigned row0 = (unsigned)bx * 128;
  if (row0 >= n) return;
  unsigned base = prefix_base(cnt, e);
  int col0 = by * 256;

  __shared__ __align__(16) u16 As[3][128 * 32];  // 24 KB
  __shared__ __align__(16) u16 Bs[3][256 * 32];  // 48 KB

  int tid = threadIdx.x;
  int w = tid >> 6, l = tid & 63;
  int wr = w >> 1, wc = w & 1;
  int lr = l & 15, g = l >> 4;

  const u16* asrc[2];
  int adst[2];
#pragma unroll
  for (int i = 0; i < 2; ++i) {
    int r = 32 * w + 16 * i + (l >> 2);
    unsigned grow = row0 + (unsigned)r;
    unsigned slot = base + (grow < n ? grow : 0);
    int chunk = (l & 3) ^ ((r >> 1) & 3);
    asrc[i] = act + (size_t)slot * IDIM + 8 * chunk;
    adst[i] = (32 * w + 16 * i) * 32;
  }
  const u16* bsrc[4];
  int bdst[4];
#pragma unroll
  for (int i = 0; i < 4; ++i) {
    int nn = 64 * w + 16 * i + (l >> 2);
    int chunk = (l & 3) ^ ((nn >> 1) & 3);
    bsrc[i] = wdT + (size_t)e * IDIM * HDIM + (size_t)(col0 + nn) * IDIM + 8 * chunk;
    bdst[i] = (64 * w + 16 * i) * 32;
  }

  int afo[4], bfo[8];
#pragma unroll
  for (int mf = 0; mf < 4; ++mf) afo[mf] = rswz(wr * 64 + mf * 16 + lr, g);
#pragma unroll
  for (int nf = 0; nf < 8; ++nf) bfo[nf] = rswz(wc * 128 + nf * 16 + lr, g);

  f32x4 acc[4][8] = {};

#define K5_STAGE(k0, buf)                        \
  do {                                           \
    gl_lds(asrc[0] + (k0), &As[buf][adst[0]]);   \
    gl_lds(asrc[1] + (k0), &As[buf][adst[1]]);   \
    gl_lds(bsrc[0] + (k0), &Bs[buf][bdst[0]]);   \
    gl_lds(bsrc[1] + (k0), &Bs[buf][bdst[1]]);   \
    gl_lds(bsrc[2] + (k0), &Bs[buf][bdst[2]]);   \
    gl_lds(bsrc[3] + (k0), &Bs[buf][bdst[3]]);   \
  } while (0)

  K5_STAGE(0, 0);
  K5_STAGE(32, 1);

  const int NK = IDIM / 32;
  int c = 0, sb = 2;
  for (int kt = 0; kt < NK; ++kt) {
    if (kt + 2 < NK) {
      K5_STAGE((kt + 2) * 32, sb);
      asm volatile("s_waitcnt vmcnt(12)" ::: "memory");
    } else if (kt + 1 < NK) {
      asm volatile("s_waitcnt vmcnt(6)" ::: "memory");
    } else {
      asm volatile("s_waitcnt vmcnt(0)" ::: "memory");
    }
    __builtin_amdgcn_s_barrier();

    short8 af[4];
#pragma unroll
    for (int mf = 0; mf < 4; ++mf) af[mf] = *(const short8*)&As[c][afo[mf]];
#pragma unroll
    for (int nf = 0; nf < 8; ++nf) {
      short8 bd = *(const short8*)&Bs[c][bfo[nf]];
#pragma unroll
      for (int mf = 0; mf < 4; ++mf)
        acc[mf][nf] = __builtin_amdgcn_mfma_f32_16x16x32_bf16(af[mf], bd, acc[mf][nf], 0, 0, 0);
    }
    __builtin_amdgcn_s_barrier();
    c = (c == 2) ? 0 : c + 1;
    sb = (sb == 2) ? 0 : sb + 1;
  }
#undef K5_STAGE

  unsigned rows_left = n - row0;
#pragma unroll
  for (int mf = 0; mf < 4; ++mf)
#pragma unroll
    for (int j = 0; j < 4; ++j) {
      int rin = wr * 64 + mf * 16 + 4 * g + j;
      if ((unsigned)rin < rows_left) {
        size_t s = base + row0 + rin;
        int token = slot_token[s];
        float wgt = slot_w[s];
        float* orow = out + (size_t)token * HDIM + col0 + wc * 128 + lr;
#pragma unroll
        for (int nf = 0; nf < 8; ++nf) atomicAdd(&orow[nf * 16], wgt * acc[mf][nf][j]);
      }
    }
}

extern "C" void kernel_launch(void* const* d_in, const int* in_sizes, int n_in,
                              void* d_out, int out_size, void* d_ws, size_t ws_size,
                              hipStream_t stream) {
  const float* x = (const float*)d_in[0];
  const float* wgate = (const float*)d_in[1];
  const float* wg = (const float*)d_in[2];
  const float* wu = (const float*)d_in[3];
  const float* wd = (const float*)d_in[4];
  float* out = (float*)d_out;
  float* logits = out + (size_t)T_TOK * HDIM;

  const size_t XBF_OFF = 132096;
  const size_t ACT_OFF = XBF_OFF + (size_t)T_TOK * HDIM * 2;
  const size_t WGT_OFF = ACT_OFF + (size_t)2 * T_TOK * IDIM * 2;
  const size_t WUT_OFF = WGT_OFF + (size_t)NE * HDIM * IDIM * 2;
  const size_t WDT_OFF = WUT_OFF + (size_t)NE * HDIM * IDIM * 2;
  const size_t NEED_T3 = WDT_OFF + (size_t)NE * IDIM * HDIM * 2;  // 167,904,256 (proven R5)
  if (ws_size < NEED_T3) return;  // loud failure

  char* ws = (char*)d_ws;
  unsigned* meta = (unsigned*)ws;
  unsigned* cnt = meta + 0;
  unsigned* cursor = meta + 8;
  u16* slot_token = (u16*)(ws + 256);
  float* slot_w = (float*)(ws + 33024);
  u16* xbf = (u16*)(ws + XBF_OFF);
  u16* act = (u16*)(ws + ACT_OFF);
  u16* wgT = (u16*)(ws + WGT_OFF);
  u16* wuT = (u16*)(ws + WUT_OFF);
  u16* wdT = (u16*)(ws + WDT_OFF);
  char* sel = (char*)act;  // dead before k4 writes act
  float* wt = (float*)((char*)act + 16384);

  hipMemsetAsync(meta, 0, 64, stream);  // cnt[8] + cursor[8]
  k01_router_cvt<<<T_TOK / 4, 256, 0, stream>>>(x, wgate, xbf, out, logits, sel, wt, cnt);
  kt_all<<<3 * 512 * NE, 256, 0, stream>>>(wg, wgT, wu, wuT, wd, wdT);
  k3_assign<<<T_TOK / 256, 256, 0, stream>>>(sel, wt, cnt, cursor, slot_token, slot_w);
  k4_gateup<<<dim3(T_TOK / 256, IDIM / 128, NE), 256, 0, stream>>>(xbf, wgT, wuT, slot_token,
                                                                   cnt, act);
  k5_down<<<dim3(T_TOK / 128, HDIM / 256, NE), 256, 0, stream>>>(act, wdT, slot_token, slot_w,
                                                                 cnt, out);
}

// Round 15
// 652.721 us; speedup vs baseline: 1.1953x; 1.1953x over previous
//
#include <hip/hip_runtime.h>
#include <math.h>

#define T_TOK 8192
#define HDIM 2048
#define IDIM 1024
#define NE 8

typedef __attribute__((ext_vector_type(8))) short short8;
typedef __attribute__((ext_vector_type(4))) float f32x4;
typedef unsigned short u16;

__device__ inline u16 f2bf(float f) {
  unsigned u = __builtin_bit_cast(unsigned, f);
  u += 0x7fffu + ((u >> 16) & 1);  // RNE
  return (u16)(u >> 16);
}
__device__ inline float bf2f(u16 u) {
  unsigned v = (unsigned)u << 16;
  return __builtin_bit_cast(float, v);
}

// async global->LDS, 16B/lane. LDS dest = wave-uniform base + lane*16.
__device__ inline void gl_lds(const u16* g, u16* l) {
  __builtin_amdgcn_global_load_lds((const __attribute__((address_space(1))) unsigned int*)g,
                                   (__attribute__((address_space(3))) unsigned int*)l, 16, 0, 0);
}

// bf16 LDS tiles [row][32] (64B rows); chunk swizzle applied on the GLOBAL
// source address (m173): position p holds global chunk p ^ ((row>>1)&3).
// Frag read of granule g: row*32 + 8*(g ^ ((row>>1)&3)) -> measured 0 conflicts.
__device__ inline int rswz(int row, int g) { return row * 32 + 8 * (g ^ ((row >> 1) & 3)); }

// ---------- ws layout ----------
// 0       meta: cnt[8] cursor[8] offsets[8] (u32)
// 256     slot_token u16[2T]  (32 KB)
// 33024   slot_w    f32[2T]   (64 KB)
// 98560   tok2slot  u16[2T]   (32 KB)   -> ends 131328
// 132096  xbf  bf16[T*H]      (33.5 MB)
// ACT     act  bf16[2T*I]     (33.5 MB)  (sel/wt stashed here pre-k4)
// WGT     wgT / wuT           (67 MB)    -> y bf16[2T*H] after k4 (exact fit)
// WDT     wdT                 (33.5 MB)  total 167,904,256 (proven R5)

// ---------------- K01: router + x->bf16 + meta-zero (x read ONCE) ----------------
// NOTE: no out-zeroing — k6 fully overwrites out, k01 writes all logits.
__global__ __launch_bounds__(256) void k01_router_cvt(const float* __restrict__ x,
                                                      const float* __restrict__ wgate,
                                                      u16* __restrict__ xb,
                                                      float* __restrict__ logits_out,
                                                      char* __restrict__ sel,
                                                      float* __restrict__ wt,
                                                      unsigned* __restrict__ cnt) {
  int wave = threadIdx.x >> 6;
  int lane = threadIdx.x & 63;
  int t = blockIdx.x * 4 + wave;
  float acc[NE];
#pragma unroll
  for (int e = 0; e < NE; ++e) acc[e] = 0.f;
  const float4* xr = (const float4*)(x + (size_t)t * HDIM);
  u16* xbrow = xb + (size_t)t * HDIM;
#pragma unroll
  for (int c = 0; c < HDIM / 256; ++c) {
    float4 xv = xr[c * 64 + lane];
    int h = (c * 64 + lane) * 4;
    ushort4 o = make_ushort4(f2bf(xv.x), f2bf(xv.y), f2bf(xv.z), f2bf(xv.w));
    *(ushort4*)(xbrow + h) = o;
    const float xs[4] = {xv.x, xv.y, xv.z, xv.w};
#pragma unroll
    for (int j = 0; j < 4; ++j) {
      const float* wrow = wgate + (size_t)(h + j) * NE;
#pragma unroll
      for (int e = 0; e < NE; ++e) acc[e] += xs[j] * wrow[e];
    }
  }
#pragma unroll
  for (int e = 0; e < NE; ++e) {
    float v = acc[e];
#pragma unroll
    for (int off = 32; off; off >>= 1) v += __shfl_xor(v, off, 64);
    acc[e] = v;
  }
  if (lane == 0) {
    float m = acc[0];
#pragma unroll
    for (int e = 0; e < NE; ++e) {
      logits_out[(size_t)t * NE + e] = acc[e];
      m = fmaxf(m, acc[e]);
    }
    float p[NE];
#pragma unroll
    for (int e = 0; e < NE; ++e) p[e] = expf(acc[e] - m);
    int b0 = 0;
    float v0 = p[0];
#pragma unroll
    for (int e = 1; e < NE; ++e)
      if (p[e] > v0) { v0 = p[e]; b0 = e; }
    int b1 = -1;
    float v1 = -1.f;
#pragma unroll
    for (int e = 0; e < NE; ++e)
      if (e != b0 && p[e] > v1) { v1 = p[e]; b1 = e; }
    float denom = v0 + v1;
    sel[t * 2 + 0] = (char)b0;
    sel[t * 2 + 1] = (char)b1;
    wt[t * 2 + 0] = v0 / denom;
    wt[t * 2 + 1] = v1 / denom;
    atomicAdd(&cnt[b0], 1u);
    atomicAdd(&cnt[b1], 1u);
  }
  if (blockIdx.x == 0 && threadIdx.x >= 8 && threadIdx.x < 24)
    cnt[threadIdx.x] = 0;  // cursor[8] + offsets[8]; cnt built atomically (memset'd)
}

// ---------------- KT: all three weight transposes, one launch ----------------
// dst[n][k] = bf16(src[k][n]) per expert.
__global__ __launch_bounds__(256) void kt_all(const float* __restrict__ wg, u16* __restrict__ wgT,
                                              const float* __restrict__ wu, u16* __restrict__ wuT,
                                              const float* __restrict__ wd, u16* __restrict__ wdT) {
  __shared__ u16 t[64][72];
  unsigned bid = blockIdx.x;
  unsigned mat = bid / (512u * NE);  // 0=wg 1=wu 2=wd
  unsigned rem = bid % (512u * NE);
  unsigned e = rem / 512u;
  unsigned tile = rem % 512u;
  int K = (mat == 2) ? IDIM : HDIM;
  int N = (mat == 2) ? HDIM : IDIM;
  const float* src = (mat == 0 ? wg : mat == 1 ? wu : wd) + (size_t)e * K * N;
  u16* dst = (mat == 0 ? wgT : mat == 1 ? wuT : wdT) + (size_t)e * K * N;
  int ntiles_n = N / 64;
  int nb = (int)(tile % ntiles_n) * 64;
  int kb = (int)(tile / ntiles_n) * 64;

  int tid = threadIdx.x;
  int lk = tid >> 4, ln = (tid & 15) * 4;
#pragma unroll
  for (int p = 0; p < 4; ++p) {
    int k = lk + 16 * p;
    float4 v = *(const float4*)(src + (size_t)(kb + k) * N + nb + ln);
    t[ln + 0][k] = f2bf(v.x);
    t[ln + 1][k] = f2bf(v.y);
    t[ln + 2][k] = f2bf(v.z);
    t[ln + 3][k] = f2bf(v.w);
  }
  __syncthreads();
  int n = tid >> 2, c = tid & 3;
  short8 o0 = *(const short8*)&t[n][c * 16];
  short8 o1 = *(const short8*)&t[n][c * 16 + 8];
  u16* d = dst + (size_t)(nb + n) * K + kb + c * 16;
  *(short8*)d = o0;
  *(short8*)(d + 8) = o1;
}

// ---------------- K2 / K3 ----------------
__global__ void k2_prefix(const unsigned* __restrict__ cnt, unsigned* __restrict__ offsets,
                          unsigned* __restrict__ cursor) {
  if (threadIdx.x == 0) {
    unsigned s = 0;
    for (int e = 0; e < NE; ++e) {
      offsets[e] = s;
      s += cnt[e];
    }
  }
  if (threadIdx.x < NE) cursor[threadIdx.x] = 0;
}

__global__ __launch_bounds__(256) void k3_assign(const char* __restrict__ sel,
                                                 const float* __restrict__ wt,
                                                 const unsigned* __restrict__ offsets,
                                                 unsigned* __restrict__ cursor,
                                                 u16* __restrict__ slot_token,
                                                 float* __restrict__ slot_w,
                                                 u16* __restrict__ tok2slot) {
  int t = blockIdx.x * 256 + threadIdx.x;
#pragma unroll
  for (int k = 0; k < 2; ++k) {
    int e = sel[t * 2 + k];
    unsigned p = atomicAdd(&cursor[e], 1u);
    unsigned s = offsets[e] + p;
    slot_token[s] = (u16)t;
    slot_w[s] = wt[t * 2 + k];
    tok2slot[t * 2 + k] = (u16)s;
  }
}

// Bijective XCD swizzle for 64x8x8 = 4096-block grids (8 XCDs, 512/XCD).
__device__ inline void xcd_decomp(int& bx, int& by, int& be) {
  unsigned bid = blockIdx.x + 64u * (blockIdx.y + 8u * blockIdx.z);
  unsigned swz = (bid & 7u) * 512u + (bid >> 3);
  bx = swz & 63u;
  unsigned rem = swz >> 6;
  by = rem & 7u;
  be = rem >> 3;
}

// ---------------- K4: MFMA gate+up + silu -> bf16 act (R9/R13 structure) ----------------
// tile 128m x 128n (g+u), 4 waves (wave 64m x 64n x 2mat), BK=32, ring-3 LDS
// (72 KB, 2 blocks/CU), depth-2 prefetch, counted vmcnt. Best-measured: ~220 us.
__global__ __launch_bounds__(256, 2) void k4_gateup(
    const u16* __restrict__ xb, const u16* __restrict__ wgT, const u16* __restrict__ wuT,
    const u16* __restrict__ slot_token, const unsigned* __restrict__ offsets,
    const unsigned* __restrict__ cnt, u16* __restrict__ act) {
  int bx, by, e;
  xcd_decomp(bx, by, e);
  unsigned n = cnt[e];
  unsigned row0 = (unsigned)bx * 128;
  if (row0 >= n) return;
  unsigned base = offsets[e];
  int col0 = by * 128;

  __shared__ __align__(16) u16 As[3][128 * 32];  // 24 KB
  __shared__ __align__(16) u16 Bg[3][128 * 32];  // 24 KB
  __shared__ __align__(16) u16 Bu[3][128 * 32];  // 24 KB

  int tid = threadIdx.x;
  int w = tid >> 6, l = tid & 63;
  int wr = w >> 1, wc = w & 1;
  int lr = l & 15, g = l >> 4;

  const u16* asrc[2];
  int adst[2];
#pragma unroll
  for (int i = 0; i < 2; ++i) {
    int r = 32 * w + 16 * i + (l >> 2);
    unsigned grow = row0 + (unsigned)r;
    unsigned slot = base + (grow < n ? grow : 0);
    int chunk = (l & 3) ^ ((r >> 1) & 3);
    asrc[i] = xb + (size_t)slot_token[slot] * HDIM + 8 * chunk;
    adst[i] = (32 * w + 16 * i) * 32;
  }
  const u16* bgsrc[2];
  const u16* busrc[2];
  int bdst[2];
#pragma unroll
  for (int i = 0; i < 2; ++i) {
    int nn = 32 * w + 16 * i + (l >> 2);
    int chunk = (l & 3) ^ ((nn >> 1) & 3);
    size_t o = (size_t)e * HDIM * IDIM + (size_t)(col0 + nn) * HDIM + 8 * chunk;
    bgsrc[i] = wgT + o;
    busrc[i] = wuT + o;
    bdst[i] = (32 * w + 16 * i) * 32;
  }

  int afo[4], bfo[4];
#pragma unroll
  for (int mf = 0; mf < 4; ++mf) afo[mf] = rswz(wr * 64 + mf * 16 + lr, g);
#pragma unroll
  for (int nf = 0; nf < 4; ++nf) bfo[nf] = rswz(wc * 64 + nf * 16 + lr, g);

  f32x4 accg[4][4] = {};
  f32x4 accu[4][4] = {};

#define K4_STAGE(k0, buf)                           \
  do {                                              \
    gl_lds(asrc[0] + (k0), &As[buf][adst[0]]);      \
    gl_lds(asrc[1] + (k0), &As[buf][adst[1]]);      \
    gl_lds(bgsrc[0] + (k0), &Bg[buf][bdst[0]]);     \
    gl_lds(bgsrc[1] + (k0), &Bg[buf][bdst[1]]);     \
    gl_lds(busrc[0] + (k0), &Bu[buf][bdst[0]]);     \
    gl_lds(busrc[1] + (k0), &Bu[buf][bdst[1]]);     \
  } while (0)

  K4_STAGE(0, 0);
  K4_STAGE(32, 1);  // 12 loads in flight

  const int NK = HDIM / 32;
  int c = 0, sb = 2;
  for (int kt = 0; kt < NK; ++kt) {
    if (kt + 2 < NK) {
      K4_STAGE((kt + 2) * 32, sb);                       // 18 in flight
      asm volatile("s_waitcnt vmcnt(12)" ::: "memory");  // tile kt landed
    } else if (kt + 1 < NK) {
      asm volatile("s_waitcnt vmcnt(6)" ::: "memory");
    } else {
      asm volatile("s_waitcnt vmcnt(0)" ::: "memory");
    }
    __builtin_amdgcn_s_barrier();

    short8 af[4];
#pragma unroll
    for (int mf = 0; mf < 4; ++mf) af[mf] = *(const short8*)&As[c][afo[mf]];
#pragma unroll
    for (int nf = 0; nf < 4; ++nf) {
      short8 bgf = *(const short8*)&Bg[c][bfo[nf]];
      short8 buf = *(const short8*)&Bu[c][bfo[nf]];
#pragma unroll
      for (int mf = 0; mf < 4; ++mf) {
        accg[mf][nf] = __builtin_amdgcn_mfma_f32_16x16x32_bf16(af[mf], bgf, accg[mf][nf], 0, 0, 0);
        accu[mf][nf] = __builtin_amdgcn_mfma_f32_16x16x32_bf16(af[mf], buf, accu[mf][nf], 0, 0, 0);
      }
    }
    __builtin_amdgcn_s_barrier();
    c = (c == 2) ? 0 : c + 1;
    sb = (sb == 2) ? 0 : sb + 1;
  }
#undef K4_STAGE

  unsigned rows_left = n - row0;
#pragma unroll
  for (int mf = 0; mf < 4; ++mf)
#pragma unroll
    for (int nf = 0; nf < 4; ++nf)
#pragma unroll
      for (int j = 0; j < 4; ++j) {
        int rin = wr * 64 + mf * 16 + 4 * g + j;
        if ((unsigned)rin < rows_left) {
          size_t s = base + row0 + rin;
          int col = col0 + wc * 64 + nf * 16 + lr;
          float gg = accg[mf][nf][j];
          float uu = accu[mf][nf][j];
          float v = (gg / (1.f + expf(-gg))) * uu;
          act[s * IDIM + col] = f2bf(v);
        }
      }
}

// ---------------- K5: MFMA down -> bf16 y (R9/R13 structure) ----------------
// tile 128m x 256n, 4 waves (64x128 each), BK=32, ring-3, depth-2, counted vmcnt.
__global__ __launch_bounds__(256, 2) void k5_down(
    const u16* __restrict__ act, const u16* __restrict__ wdT,
    const unsigned* __restrict__ offsets, const unsigned* __restrict__ cnt,
    u16* __restrict__ y) {
  int bx, by, e;
  xcd_decomp(bx, by, e);
  unsigned n = cnt[e];
  unsigned row0 = (unsigned)bx * 128;
  if (row0 >= n) return;
  unsigned base = offsets[e];
  int col0 = by * 256;

  __shared__ __align__(16) u16 As[3][128 * 32];  // 24 KB
  __shared__ __align__(16) u16 Bs[3][256 * 32];  // 48 KB

  int tid = threadIdx.x;
  int w = tid >> 6, l = tid & 63;
  int wr = w >> 1, wc = w & 1;
  int lr = l & 15, g = l >> 4;

  const u16* asrc[2];
  int adst[2];
#pragma unroll
  for (int i = 0; i < 2; ++i) {
    int r = 32 * w + 16 * i + (l >> 2);
    unsigned grow = row0 + (unsigned)r;
    unsigned slot = base + (grow < n ? grow : 0);
    int chunk = (l & 3) ^ ((r >> 1) & 3);
    asrc[i] = act + (size_t)slot * IDIM + 8 * chunk;
    adst[i] = (32 * w + 16 * i) * 32;
  }
  const u16* bsrc[4];
  int bdst[4];
#pragma unroll
  for (int i = 0; i < 4; ++i) {
    int nn = 64 * w + 16 * i + (l >> 2);
    int chunk = (l & 3) ^ ((nn >> 1) & 3);
    bsrc[i] = wdT + (size_t)e * IDIM * HDIM + (size_t)(col0 + nn) * IDIM + 8 * chunk;
    bdst[i] = (64 * w + 16 * i) * 32;
  }

  int afo[4], bfo[8];
#pragma unroll
  for (int mf = 0; mf < 4; ++mf) afo[mf] = rswz(wr * 64 + mf * 16 + lr, g);
#pragma unroll
  for (int nf = 0; nf < 8; ++nf) bfo[nf] = rswz(wc * 128 + nf * 16 + lr, g);

  f32x4 acc[4][8] = {};

#define K5_STAGE(k0, buf)                        \
  do {                                           \
    gl_lds(asrc[0] + (k0), &As[buf][adst[0]]);   \
    gl_lds(asrc[1] + (k0), &As[buf][adst[1]]);   \
    gl_lds(bsrc[0] + (k0), &Bs[buf][bdst[0]]);   \
    gl_lds(bsrc[1] + (k0), &Bs[buf][bdst[1]]);   \
    gl_lds(bsrc[2] + (k0), &Bs[buf][bdst[2]]);   \
    gl_lds(bsrc[3] + (k0), &Bs[buf][bdst[3]]);   \
  } while (0)

  K5_STAGE(0, 0);
  K5_STAGE(32, 1);

  const int NK = IDIM / 32;
  int c = 0, sb = 2;
  for (int kt = 0; kt < NK; ++kt) {
    if (kt + 2 < NK) {
      K5_STAGE((kt + 2) * 32, sb);
      asm volatile("s_waitcnt vmcnt(12)" ::: "memory");
    } else if (kt + 1 < NK) {
      asm volatile("s_waitcnt vmcnt(6)" ::: "memory");
    } else {
      asm volatile("s_waitcnt vmcnt(0)" ::: "memory");
    }
    __builtin_amdgcn_s_barrier();

    short8 af[4];
#pragma unroll
    for (int mf = 0; mf < 4; ++mf) af[mf] = *(const short8*)&As[c][afo[mf]];
#pragma unroll
    for (int nf = 0; nf < 8; ++nf) {
      short8 bd = *(const short8*)&Bs[c][bfo[nf]];
#pragma unroll
      for (int mf = 0; mf < 4; ++mf)
        acc[mf][nf] = __builtin_amdgcn_mfma_f32_16x16x32_bf16(af[mf], bd, acc[mf][nf], 0, 0, 0);
    }
    __builtin_amdgcn_s_barrier();
    c = (c == 2) ? 0 : c + 1;
    sb = (sb == 2) ? 0 : sb + 1;
  }
#undef K5_STAGE

  unsigned rows_left = n - row0;
#pragma unroll
  for (int mf = 0; mf < 4; ++mf)
#pragma unroll
    for (int j = 0; j < 4; ++j) {
      int rin = wr * 64 + mf * 16 + 4 * g + j;
      if ((unsigned)rin < rows_left) {
        size_t s = base + row0 + rin;
        u16* yrow = y + s * HDIM + col0 + wc * 128 + lr;
#pragma unroll
        for (int nf = 0; nf < 8; ++nf) yrow[nf * 16] = f2bf(acc[mf][nf][j]);
      }
    }
}

// ---------------- K6: combine out[t] = w0*y[s0] + w1*y[s1] ----------------
__global__ __launch_bounds__(512) void k6_combine(const u16* __restrict__ y,
                                                  const u16* __restrict__ tok2slot,
                                                  const float* __restrict__ slot_w,
                                                  float* __restrict__ out) {
  unsigned idx = blockIdx.x * 512 + threadIdx.x;  // one per 8 elems
  int t = idx >> 8;                               // HDIM/8 = 256 chunks per row
  int off = (idx & 255) * 8;
  int s0 = tok2slot[t * 2 + 0];
  int s1 = tok2slot[t * 2 + 1];
  float w0 = slot_w[s0];
  float w1 = slot_w[s1];
  short8 a = *(const short8*)(y + (size_t)s0 * HDIM + off);
  short8 b = *(const short8*)(y + (size_t)s1 * HDIM + off);
  float* o = out + (size_t)t * HDIM + off;
  float4 o0, o1;
  o0.x = w0 * bf2f((u16)a[0]) + w1 * bf2f((u16)b[0]);
  o0.y = w0 * bf2f((u16)a[1]) + w1 * bf2f((u16)b[1]);
  o0.z = w0 * bf2f((u16)a[2]) + w1 * bf2f((u16)b[2]);
  o0.w = w0 * bf2f((u16)a[3]) + w1 * bf2f((u16)b[3]);
  o1.x = w0 * bf2f((u16)a[4]) + w1 * bf2f((u16)b[4]);
  o1.y = w0 * bf2f((u16)a[5]) + w1 * bf2f((u16)b[5]);
  o1.z = w0 * bf2f((u16)a[6]) + w1 * bf2f((u16)b[6]);
  o1.w = w0 * bf2f((u16)a[7]) + w1 * bf2f((u16)b[7]);
  *(float4*)o = o0;
  *(float4*)(o + 4) = o1;
}

extern "C" void kernel_launch(void* const* d_in, const int* in_sizes, int n_in,
                              void* d_out, int out_size, void* d_ws, size_t ws_size,
                              hipStream_t stream) {
  const float* x = (const float*)d_in[0];
  const float* wgate = (const float*)d_in[1];
  const float* wg = (const float*)d_in[2];
  const float* wu = (const float*)d_in[3];
  const float* wd = (const float*)d_in[4];
  float* out = (float*)d_out;
  float* logits = out + (size_t)T_TOK * HDIM;

  const size_t XBF_OFF = 132096;
  const size_t ACT_OFF = XBF_OFF + (size_t)T_TOK * HDIM * 2;
  const size_t WGT_OFF = ACT_OFF + (size_t)2 * T_TOK * IDIM * 2;
  const size_t WUT_OFF = WGT_OFF + (size_t)NE * HDIM * IDIM * 2;
  const size_t WDT_OFF = WUT_OFF + (size_t)NE * HDIM * IDIM * 2;
  const size_t NEED_T3 = WDT_OFF + (size_t)NE * IDIM * HDIM * 2;  // 167,904,256 (proven R5)
  if (ws_size < NEED_T3) return;  // loud failure

  char* ws = (char*)d_ws;
  unsigned* meta = (unsigned*)ws;
  unsigned* cnt = meta + 0;
  unsigned* cursor = meta + 8;
  unsigned* offsets = meta + 16;
  u16* slot_token = (u16*)(ws + 256);
  float* slot_w = (float*)(ws + 33024);
  u16* tok2slot = (u16*)(ws + 98560);
  u16* xbf = (u16*)(ws + XBF_OFF);
  u16* act = (u16*)(ws + ACT_OFF);
  u16* wgT = (u16*)(ws + WGT_OFF);
  u16* wuT = (u16*)(ws + WUT_OFF);
  u16* wdT = (u16*)(ws + WDT_OFF);
  u16* y = (u16*)(ws + WGT_OFF);  // reuses wgT+wuT (dead after k4)
  char* sel = (char*)act;         // dead before k4 writes act
  float* wt = (float*)((char*)act + 16384);

  hipMemsetAsync(cnt, 0, 32, stream);
  k01_router_cvt<<<T_TOK / 4, 256, 0, stream>>>(x, wgate, xbf, logits, sel, wt, cnt);
  kt_all<<<3 * 512 * NE, 256, 0, stream>>>(wg, wgT, wu, wuT, wd, wdT);
  k2_prefix<<<1, 64, 0, stream>>>(cnt, offsets, cursor);
  k3_assign<<<T_TOK / 256, 256, 0, stream>>>(sel, wt, offsets, cursor, slot_token, slot_w,
                                             tok2slot);
  k4_gateup<<<dim3(T_TOK / 128, IDIM / 128, NE), 256, 0, stream>>>(xbf, wgT, wuT, slot_token,
                                                                   offsets, cnt, act);
  k5_down<<<dim3(T_TOK / 128, HDIM / 256, NE), 256, 0, stream>>>(act, wdT, offsets, cnt, y);
  k6_combine<<<T_TOK * HDIM / 8 / 512, 512, 0, stream>>>(y, tok2slot, slot_w, out);
}

// Round 16
// 626.510 us; speedup vs baseline: 1.2453x; 1.0418x over previous
//
#include <hip/hip_runtime.h>
#include <math.h>

#define T_TOK 8192
#define HDIM 2048
#define IDIM 1024
#define NE 8

typedef __attribute__((ext_vector_type(8))) short short8;
typedef __attribute__((ext_vector_type(4))) float f32x4;
typedef unsigned short u16;

__device__ inline u16 f2bf(float f) {
  unsigned u = __builtin_bit_cast(unsigned, f);
  u += 0x7fffu + ((u >> 16) & 1);  // RNE
  return (u16)(u >> 16);
}
__device__ inline float bf2f(u16 u) {
  unsigned v = (unsigned)u << 16;
  return __builtin_bit_cast(float, v);
}

// async global->LDS, 16B/lane. LDS dest = wave-uniform base + lane*16.
__device__ inline void gl_lds(const u16* g, u16* l) {
  __builtin_amdgcn_global_load_lds((const __attribute__((address_space(1))) unsigned int*)g,
                                   (__attribute__((address_space(3))) unsigned int*)l, 16, 0, 0);
}

// bf16 LDS tiles [row][32] (64B rows); chunk swizzle applied on the GLOBAL
// source address (m173): position p holds global chunk p ^ ((row>>1)&3).
// Frag read of granule g: row*32 + 8*(g ^ ((row>>1)&3)) -> measured 0 conflicts.
__device__ inline int rswz(int row, int g) { return row * 32 + 8 * (g ^ ((row >> 1) & 3)); }

// ---------- ws layout ----------
// 0       meta: cnt[8] cursor[8] (u32)
// 256     slot_token u16[2T]  (32 KB)
// 33024   slot_w    f32[2T]   (64 KB)
// 98560   tok2slot  u16[2T]   (32 KB)   -> ends 131328
// 132096  xbf  bf16[T*H]      (33.5 MB)
// ACT     act  bf16[2T*I]     (33.5 MB)  (sel/wt stashed here pre-k4)
// WGT     wgT / wuT           (67 MB)    -> y bf16[2T*H] after k4 (exact fit)
// WDT     wdT                 (33.5 MB)  total 167,904,256 (proven R5)

// ---------------- K0T: FUSED router+cvt (blocks 0..2047) & weight transpose
// (blocks 2048..14335). Independent work; fusing lets VALU-bound router blocks
// overlap BW-bound transpose blocks inside one dispatch (only in-stream overlap
// tool). Router: one wave/token, writes xbf + logits + sel/wt + cnt atomics;
// block 0 also zeroes cursor. Transpose: dst[n][k] = bf16(src[k][n]).
__global__ __launch_bounds__(256) void k0t_fused(
    const float* __restrict__ x, const float* __restrict__ wgate, u16* __restrict__ xb,
    float* __restrict__ logits_out, char* __restrict__ sel, float* __restrict__ wt,
    unsigned* __restrict__ cnt, const float* __restrict__ wg, u16* __restrict__ wgT,
    const float* __restrict__ wu, u16* __restrict__ wuT, const float* __restrict__ wd,
    u16* __restrict__ wdT) {
  __shared__ u16 t[64][72];
  unsigned bid = blockIdx.x;
  if (bid < T_TOK / 4) {
    // ---- router + x->bf16 ----
    int wave = threadIdx.x >> 6;
    int lane = threadIdx.x & 63;
    int tok = bid * 4 + wave;
    float acc[NE];
#pragma unroll
    for (int e = 0; e < NE; ++e) acc[e] = 0.f;
    const float4* xr = (const float4*)(x + (size_t)tok * HDIM);
    u16* xbrow = xb + (size_t)tok * HDIM;
#pragma unroll
    for (int c = 0; c < HDIM / 256; ++c) {
      float4 xv = xr[c * 64 + lane];
      int h = (c * 64 + lane) * 4;
      ushort4 o = make_ushort4(f2bf(xv.x), f2bf(xv.y), f2bf(xv.z), f2bf(xv.w));
      *(ushort4*)(xbrow + h) = o;
      const float xs[4] = {xv.x, xv.y, xv.z, xv.w};
#pragma unroll
      for (int j = 0; j < 4; ++j) {
        const float* wrow = wgate + (size_t)(h + j) * NE;
#pragma unroll
        for (int e = 0; e < NE; ++e) acc[e] += xs[j] * wrow[e];
      }
    }
#pragma unroll
    for (int e = 0; e < NE; ++e) {
      float v = acc[e];
#pragma unroll
      for (int off = 32; off; off >>= 1) v += __shfl_xor(v, off, 64);
      acc[e] = v;
    }
    if (lane == 0) {
      float m = acc[0];
#pragma unroll
      for (int e = 0; e < NE; ++e) {
        logits_out[(size_t)tok * NE + e] = acc[e];
        m = fmaxf(m, acc[e]);
      }
      float p[NE];
#pragma unroll
      for (int e = 0; e < NE; ++e) p[e] = expf(acc[e] - m);
      int b0 = 0;
      float v0 = p[0];
#pragma unroll
      for (int e = 1; e < NE; ++e)
        if (p[e] > v0) { v0 = p[e]; b0 = e; }
      int b1 = -1;
      float v1 = -1.f;
#pragma unroll
      for (int e = 0; e < NE; ++e)
        if (e != b0 && p[e] > v1) { v1 = p[e]; b1 = e; }
      float denom = v0 + v1;
      sel[tok * 2 + 0] = (char)b0;
      sel[tok * 2 + 1] = (char)b1;
      wt[tok * 2 + 0] = v0 / denom;
      wt[tok * 2 + 1] = v1 / denom;
      atomicAdd(&cnt[b0], 1u);
      atomicAdd(&cnt[b1], 1u);
    }
    if (bid == 0 && threadIdx.x >= 8 && threadIdx.x < 16)
      cnt[threadIdx.x] = 0;  // cursor[8] (cnt itself memset'd before launch)
  } else {
    // ---- weight transpose+cvt ----
    unsigned tb = bid - T_TOK / 4;
    unsigned mat = tb / (512u * NE);  // 0=wg 1=wu 2=wd
    unsigned rem = tb % (512u * NE);
    unsigned e = rem / 512u;
    unsigned tile = rem % 512u;
    int K = (mat == 2) ? IDIM : HDIM;
    int N = (mat == 2) ? HDIM : IDIM;
    const float* src = (mat == 0 ? wg : mat == 1 ? wu : wd) + (size_t)e * K * N;
    u16* dst = (mat == 0 ? wgT : mat == 1 ? wuT : wdT) + (size_t)e * K * N;
    int ntiles_n = N / 64;
    int nb = (int)(tile % ntiles_n) * 64;
    int kb = (int)(tile / ntiles_n) * 64;

    int tid = threadIdx.x;
    int lk = tid >> 4, ln = (tid & 15) * 4;
#pragma unroll
    for (int p = 0; p < 4; ++p) {
      int k = lk + 16 * p;
      float4 v = *(const float4*)(src + (size_t)(kb + k) * N + nb + ln);
      t[ln + 0][k] = f2bf(v.x);
      t[ln + 1][k] = f2bf(v.y);
      t[ln + 2][k] = f2bf(v.z);
      t[ln + 3][k] = f2bf(v.w);
    }
    __syncthreads();
    int n = tid >> 2, c = tid & 3;
    short8 o0 = *(const short8*)&t[n][c * 16];
    short8 o1 = *(const short8*)&t[n][c * 16 + 8];
    u16* d = dst + (size_t)(nb + n) * K + kb + c * 16;
    *(short8*)d = o0;
    *(short8*)(d + 8) = o1;
  }
}

// ---------------- K3: slot assignment (local prefix, replaces k2+k3) ----------------
__global__ __launch_bounds__(256) void k3_assign(const char* __restrict__ sel,
                                                 const float* __restrict__ wt,
                                                 const unsigned* __restrict__ cnt,
                                                 unsigned* __restrict__ cursor,
                                                 u16* __restrict__ slot_token,
                                                 float* __restrict__ slot_w,
                                                 u16* __restrict__ tok2slot) {
  unsigned offv[NE];
  unsigned s = 0;
#pragma unroll
  for (int e = 0; e < NE; ++e) {
    offv[e] = s;
    s += cnt[e];
  }
  int t = blockIdx.x * 256 + threadIdx.x;
#pragma unroll
  for (int k = 0; k < 2; ++k) {
    int e = sel[t * 2 + k];
    unsigned p = atomicAdd(&cursor[e], 1u);
    unsigned slot = offv[e] + p;
    slot_token[slot] = (u16)t;
    slot_w[slot] = wt[t * 2 + k];
    tok2slot[t * 2 + k] = (u16)slot;
  }
}

// Bijective XCD swizzle for 64x8x8 = 4096-block grids (8 XCDs, 512/XCD).
__device__ inline void xcd_decomp(int& bx, int& by, int& be) {
  unsigned bid = blockIdx.x + 64u * (blockIdx.y + 8u * blockIdx.z);
  unsigned swz = (bid & 7u) * 512u + (bid >> 3);
  bx = swz & 63u;
  unsigned rem = swz >> 6;
  by = rem & 7u;
  be = rem >> 3;
}

// local exclusive-prefix over cnt (8 uniform L2-hot loads)
__device__ inline unsigned prefix_base(const unsigned* cnt, int e) {
  unsigned b = 0;
#pragma unroll
  for (int i = 0; i < NE; ++i) b += (i < e) ? cnt[i] : 0u;
  return b;
}

// ---------------- K4: MFMA gate+up + silu -> bf16 act (R9/R13 structure) ----------------
// tile 128m x 128n (g+u), 4 waves, BK=32, ring-3 LDS (72 KB, 2 blocks/CU),
// depth-2 prefetch, counted vmcnt. Best-measured: ~221 us, MfmaUtil 27%.
__global__ __launch_bounds__(256, 2) void k4_gateup(
    const u16* __restrict__ xb, const u16* __restrict__ wgT, const u16* __restrict__ wuT,
    const u16* __restrict__ slot_token, const unsigned* __restrict__ cnt,
    u16* __restrict__ act) {
  int bx, by, e;
  xcd_decomp(bx, by, e);
  unsigned n = cnt[e];
  unsigned row0 = (unsigned)bx * 128;
  if (row0 >= n) return;
  unsigned base = prefix_base(cnt, e);
  int col0 = by * 128;

  __shared__ __align__(16) u16 As[3][128 * 32];  // 24 KB
  __shared__ __align__(16) u16 Bg[3][128 * 32];  // 24 KB
  __shared__ __align__(16) u16 Bu[3][128 * 32];  // 24 KB

  int tid = threadIdx.x;
  int w = tid >> 6, l = tid & 63;
  int wr = w >> 1, wc = w & 1;
  int lr = l & 15, g = l >> 4;

  const u16* asrc[2];
  int adst[2];
#pragma unroll
  for (int i = 0; i < 2; ++i) {
    int r = 32 * w + 16 * i + (l >> 2);
    unsigned grow = row0 + (unsigned)r;
    unsigned slot = base + (grow < n ? grow : 0);
    int chunk = (l & 3) ^ ((r >> 1) & 3);
    asrc[i] = xb + (size_t)slot_token[slot] * HDIM + 8 * chunk;
    adst[i] = (32 * w + 16 * i) * 32;
  }
  const u16* bgsrc[2];
  const u16* busrc[2];
  int bdst[2];
#pragma unroll
  for (int i = 0; i < 2; ++i) {
    int nn = 32 * w + 16 * i + (l >> 2);
    int chunk = (l & 3) ^ ((nn >> 1) & 3);
    size_t o = (size_t)e * HDIM * IDIM + (size_t)(col0 + nn) * HDIM + 8 * chunk;
    bgsrc[i] = wgT + o;
    busrc[i] = wuT + o;
    bdst[i] = (32 * w + 16 * i) * 32;
  }

  int afo[4], bfo[4];
#pragma unroll
  for (int mf = 0; mf < 4; ++mf) afo[mf] = rswz(wr * 64 + mf * 16 + lr, g);
#pragma unroll
  for (int nf = 0; nf < 4; ++nf) bfo[nf] = rswz(wc * 64 + nf * 16 + lr, g);

  f32x4 accg[4][4] = {};
  f32x4 accu[4][4] = {};

#define K4_STAGE(k0, buf)                           \
  do {                                              \
    gl_lds(asrc[0] + (k0), &As[buf][adst[0]]);      \
    gl_lds(asrc[1] + (k0), &As[buf][adst[1]]);      \
    gl_lds(bgsrc[0] + (k0), &Bg[buf][bdst[0]]);     \
    gl_lds(bgsrc[1] + (k0), &Bg[buf][bdst[1]]);     \
    gl_lds(busrc[0] + (k0), &Bu[buf][bdst[0]]);     \
    gl_lds(busrc[1] + (k0), &Bu[buf][bdst[1]]);     \
  } while (0)

  K4_STAGE(0, 0);
  K4_STAGE(32, 1);  // 12 loads in flight

  const int NK = HDIM / 32;
  int c = 0, sb = 2;
  for (int kt = 0; kt < NK; ++kt) {
    if (kt + 2 < NK) {
      K4_STAGE((kt + 2) * 32, sb);                       // 18 in flight
      asm volatile("s_waitcnt vmcnt(12)" ::: "memory");  // tile kt landed
    } else if (kt + 1 < NK) {
      asm volatile("s_waitcnt vmcnt(6)" ::: "memory");
    } else {
      asm volatile("s_waitcnt vmcnt(0)" ::: "memory");
    }
    __builtin_amdgcn_s_barrier();

    short8 af[4];
#pragma unroll
    for (int mf = 0; mf < 4; ++mf) af[mf] = *(const short8*)&As[c][afo[mf]];
#pragma unroll
    for (int nf = 0; nf < 4; ++nf) {
      short8 bgf = *(const short8*)&Bg[c][bfo[nf]];
      short8 buf = *(const short8*)&Bu[c][bfo[nf]];
#pragma unroll
      for (int mf = 0; mf < 4; ++mf) {
        accg[mf][nf] = __builtin_amdgcn_mfma_f32_16x16x32_bf16(af[mf], bgf, accg[mf][nf], 0, 0, 0);
        accu[mf][nf] = __builtin_amdgcn_mfma_f32_16x16x32_bf16(af[mf], buf, accu[mf][nf], 0, 0, 0);
      }
    }
    __builtin_amdgcn_s_barrier();
    c = (c == 2) ? 0 : c + 1;
    sb = (sb == 2) ? 0 : sb + 1;
  }
#undef K4_STAGE

  unsigned rows_left = n - row0;
#pragma unroll
  for (int mf = 0; mf < 4; ++mf)
#pragma unroll
    for (int nf = 0; nf < 4; ++nf)
#pragma unroll
      for (int j = 0; j < 4; ++j) {
        int rin = wr * 64 + mf * 16 + 4 * g + j;
        if ((unsigned)rin < rows_left) {
          size_t s = base + row0 + rin;
          int col = col0 + wc * 64 + nf * 16 + lr;
          float gg = accg[mf][nf][j];
          float uu = accu[mf][nf][j];
          float v = (gg / (1.f + expf(-gg))) * uu;
          act[s * IDIM + col] = f2bf(v);
        }
      }
}

// ---------------- K5: MFMA down -> bf16 y (R9/R13 structure) ----------------
// tile 128m x 256n, 4 waves (64x128 each), BK=32, ring-3, depth-2, counted vmcnt.
__global__ __launch_bounds__(256, 2) void k5_down(
    const u16* __restrict__ act, const u16* __restrict__ wdT,
    const unsigned* __restrict__ cnt, u16* __restrict__ y) {
  int bx, by, e;
  xcd_decomp(bx, by, e);
  unsigned n = cnt[e];
  unsigned row0 = (unsigned)bx * 128;
  if (row0 >= n) return;
  unsigned base = prefix_base(cnt, e);
  int col0 = by * 256;

  __shared__ __align__(16) u16 As[3][128 * 32];  // 24 KB
  __shared__ __align__(16) u16 Bs[3][256 * 32];  // 48 KB

  int tid = threadIdx.x;
  int w = tid >> 6, l = tid & 63;
  int wr = w >> 1, wc = w & 1;
  int lr = l & 15, g = l >> 4;

  const u16* asrc[2];
  int adst[2];
#pragma unroll
  for (int i = 0; i < 2; ++i) {
    int r = 32 * w + 16 * i + (l >> 2);
    unsigned grow = row0 + (unsigned)r;
    unsigned slot = base + (grow < n ? grow : 0);
    int chunk = (l & 3) ^ ((r >> 1) & 3);
    asrc[i] = act + (size_t)slot * IDIM + 8 * chunk;
    adst[i] = (32 * w + 16 * i) * 32;
  }
  const u16* bsrc[4];
  int bdst[4];
#pragma unroll
  for (int i = 0; i < 4; ++i) {
    int nn = 64 * w + 16 * i + (l >> 2);
    int chunk = (l & 3) ^ ((nn >> 1) & 3);
    bsrc[i] = wdT + (size_t)e * IDIM * HDIM + (size_t)(col0 + nn) * IDIM + 8 * chunk;
    bdst[i] = (64 * w + 16 * i) * 32;
  }

  int afo[4], bfo[8];
#pragma unroll
  for (int mf = 0; mf < 4; ++mf) afo[mf] = rswz(wr * 64 + mf * 16 + lr, g);
#pragma unroll
  for (int nf = 0; nf < 8; ++nf) bfo[nf] = rswz(wc * 128 + nf * 16 + lr, g);

  f32x4 acc[4][8] = {};

#define K5_STAGE(k0, buf)                        \
  do {                                           \
    gl_lds(asrc[0] + (k0), &As[buf][adst[0]]);   \
    gl_lds(asrc[1] + (k0), &As[buf][adst[1]]);   \
    gl_lds(bsrc[0] + (k0), &Bs[buf][bdst[0]]);   \
    gl_lds(bsrc[1] + (k0), &Bs[buf][bdst[1]]);   \
    gl_lds(bsrc[2] + (k0), &Bs[buf][bdst[2]]);   \
    gl_lds(bsrc[3] + (k0), &Bs[buf][bdst[3]]);   \
  } while (0)

  K5_STAGE(0, 0);
  K5_STAGE(32, 1);

  const int NK = IDIM / 32;
  int c = 0, sb = 2;
  for (int kt = 0; kt < NK; ++kt) {
    if (kt + 2 < NK) {
      K5_STAGE((kt + 2) * 32, sb);
      asm volatile("s_waitcnt vmcnt(12)" ::: "memory");
    } else if (kt + 1 < NK) {
      asm volatile("s_waitcnt vmcnt(6)" ::: "memory");
    } else {
      asm volatile("s_waitcnt vmcnt(0)" ::: "memory");
    }
    __builtin_amdgcn_s_barrier();

    short8 af[4];
#pragma unroll
    for (int mf = 0; mf < 4; ++mf) af[mf] = *(const short8*)&As[c][afo[mf]];
#pragma unroll
    for (int nf = 0; nf < 8; ++nf) {
      short8 bd = *(const short8*)&Bs[c][bfo[nf]];
#pragma unroll
      for (int mf = 0; mf < 4; ++mf)
        acc[mf][nf] = __builtin_amdgcn_mfma_f32_16x16x32_bf16(af[mf], bd, acc[mf][nf], 0, 0, 0);
    }
    __builtin_amdgcn_s_barrier();
    c = (c == 2) ? 0 : c + 1;
    sb = (sb == 2) ? 0 : sb + 1;
  }
#undef K5_STAGE

  unsigned rows_left = n - row0;
#pragma unroll
  for (int mf = 0; mf < 4; ++mf)
#pragma unroll
    for (int j = 0; j < 4; ++j) {
      int rin = wr * 64 + mf * 16 + 4 * g + j;
      if ((unsigned)rin < rows_left) {
        size_t s = base + row0 + rin;
        u16* yrow = y + s * HDIM + col0 + wc * 128 + lr;
#pragma unroll
        for (int nf = 0; nf < 8; ++nf) yrow[nf * 16] = f2bf(acc[mf][nf][j]);
      }
    }
}

// ---------------- K6: combine out[t] = w0*y[s0] + w1*y[s1] ----------------
__global__ __launch_bounds__(512) void k6_combine(const u16* __restrict__ y,
                                                  const u16* __restrict__ tok2slot,
                                                  const float* __restrict__ slot_w,
                                                  float* __restrict__ out) {
  unsigned idx = blockIdx.x * 512 + threadIdx.x;  // one per 8 elems
  int t = idx >> 8;                               // HDIM/8 = 256 chunks per row
  int off = (idx & 255) * 8;
  int s0 = tok2slot[t * 2 + 0];
  int s1 = tok2slot[t * 2 + 1];
  float w0 = slot_w[s0];
  float w1 = slot_w[s1];
  short8 a = *(const short8*)(y + (size_t)s0 * HDIM + off);
  short8 b = *(const short8*)(y + (size_t)s1 * HDIM + off);
  float* o = out + (size_t)t * HDIM + off;
  float4 o0, o1;
  o0.x = w0 * bf2f((u16)a[0]) + w1 * bf2f((u16)b[0]);
  o0.y = w0 * bf2f((u16)a[1]) + w1 * bf2f((u16)b[1]);
  o0.z = w0 * bf2f((u16)a[2]) + w1 * bf2f((u16)b[2]);
  o0.w = w0 * bf2f((u16)a[3]) + w1 * bf2f((u16)b[3]);
  o1.x = w0 * bf2f((u16)a[4]) + w1 * bf2f((u16)b[4]);
  o1.y = w0 * bf2f((u16)a[5]) + w1 * bf2f((u16)b[5]);
  o1.z = w0 * bf2f((u16)a[6]) + w1 * bf2f((u16)b[6]);
  o1.w = w0 * bf2f((u16)a[7]) + w1 * bf2f((u16)b[7]);
  *(float4*)o = o0;
  *(float4*)(o + 4) = o1;
}

extern "C" void kernel_launch(void* const* d_in, const int* in_sizes, int n_in,
                              void* d_out, int out_size, void* d_ws, size_t ws_size,
                              hipStream_t stream) {
  const float* x = (const float*)d_in[0];
  const float* wgate = (const float*)d_in[1];
  const float* wg = (const float*)d_in[2];
  const float* wu = (const float*)d_in[3];
  const float* wd = (const float*)d_in[4];
  float* out = (float*)d_out;
  float* logits = out + (size_t)T_TOK * HDIM;

  const size_t XBF_OFF = 132096;
  const size_t ACT_OFF = XBF_OFF + (size_t)T_TOK * HDIM * 2;
  const size_t WGT_OFF = ACT_OFF + (size_t)2 * T_TOK * IDIM * 2;
  const size_t WUT_OFF = WGT_OFF + (size_t)NE * HDIM * IDIM * 2;
  const size_t WDT_OFF = WUT_OFF + (size_t)NE * HDIM * IDIM * 2;
  const size_t NEED_T3 = WDT_OFF + (size_t)NE * IDIM * HDIM * 2;  // 167,904,256 (proven R5)
  if (ws_size < NEED_T3) return;  // loud failure

  char* ws = (char*)d_ws;
  unsigned* meta = (unsigned*)ws;
  unsigned* cnt = meta + 0;
  unsigned* cursor = meta + 8;
  u16* slot_token = (u16*)(ws + 256);
  float* slot_w = (float*)(ws + 33024);
  u16* tok2slot = (u16*)(ws + 98560);
  u16* xbf = (u16*)(ws + XBF_OFF);
  u16* act = (u16*)(ws + ACT_OFF);
  u16* wgT = (u16*)(ws + WGT_OFF);
  u16* wuT = (u16*)(ws + WUT_OFF);
  u16* wdT = (u16*)(ws + WDT_OFF);
  u16* y = (u16*)(ws + WGT_OFF);  // reuses wgT+wuT (dead after k4)
  char* sel = (char*)act;         // dead before k4 writes act
  float* wt = (float*)((char*)act + 16384);

  hipMemsetAsync(cnt, 0, 32, stream);
  k0t_fused<<<T_TOK / 4 + 3 * 512 * NE, 256, 0, stream>>>(
      x, wgate, xbf, logits, sel, wt, cnt, wg, wgT, wu, wuT, wd, wdT);
  k3_assign<<<T_TOK / 256, 256, 0, stream>>>(sel, wt, cnt, cursor, slot_token, slot_w, tok2slot);
  k4_gateup<<<dim3(T_TOK / 128, IDIM / 128, NE), 256, 0, stream>>>(xbf, wgT, wuT, slot_token,
                                                                   cnt, act);
  k5_down<<<dim3(T_TOK / 128, HDIM / 256, NE), 256, 0, stream>>>(act, wdT, cnt, y);
  k6_combine<<<T_TOK * HDIM / 8 / 512, 512, 0, stream>>>(y, tok2slot, slot_w, out);
}

// Round 17
// 623.182 us; speedup vs baseline: 1.2519x; 1.0053x over previous
//
#include <hip/hip_runtime.h>
#include <math.h>

#define T_TOK 8192
#define HDIM 2048
#define IDIM 1024
#define NE 8

typedef __attribute__((ext_vector_type(8))) short short8;
typedef __attribute__((ext_vector_type(4))) float f32x4;
typedef unsigned short u16;

__device__ inline u16 f2bf(float f) {
  unsigned u = __builtin_bit_cast(unsigned, f);
  u += 0x7fffu + ((u >> 16) & 1);  // RNE
  return (u16)(u >> 16);
}
__device__ inline float bf2f(u16 u) {
  unsigned v = (unsigned)u << 16;
  return __builtin_bit_cast(float, v);
}

// async global->LDS, 16B/lane. LDS dest = wave-uniform base + lane*16.
__device__ inline void gl_lds(const u16* g, u16* l) {
  __builtin_amdgcn_global_load_lds((const __attribute__((address_space(1))) unsigned int*)g,
                                   (__attribute__((address_space(3))) unsigned int*)l, 16, 0, 0);
}

// bf16 LDS tiles [row][32] (64B rows); chunk swizzle applied on the GLOBAL
// source address (m173): position p holds global chunk p ^ ((row>>1)&3).
// Frag read of granule g: row*32 + 8*(g ^ ((row>>1)&3)) -> measured 0 conflicts.
__device__ inline int rswz(int row, int g) { return row * 32 + 8 * (g ^ ((row >> 1) & 3)); }

// ---------- ws layout ----------
// 0       meta: cnt[8] cursor[8] (u32)
// 256     slot_token u16[2T]  (32 KB)
// 33024   slot_w    f32[2T]   (64 KB)
// 98560   tok2slot  u16[2T]   (32 KB)   -> ends 131328
// 132096  xbf  bf16[T*H]      (33.5 MB)
// ACT     act  bf16[2T*I]     (33.5 MB)  (sel/wt stashed here pre-k4)
// WGT     wgT / wuT           (67 MB)    -> y bf16[2T*H] after k4 (exact fit)
// WDT     wdT                 (33.5 MB)  total 167,904,256 (proven R5)

// ---------------- K0T: FUSED router+cvt (blocks 0..2047) & weight transpose
// (blocks 2048..8191). Transpose arm: 64n x 128k strip per block (2 sub-tiles),
// all 8 float4 loads upfront (2x latency amortization), one sync, 256B
// contiguous per dst row.
__global__ __launch_bounds__(256) void k0t_fused(
    const float* __restrict__ x, const float* __restrict__ wgate, u16* __restrict__ xb,
    float* __restrict__ logits_out, char* __restrict__ sel, float* __restrict__ wt,
    unsigned* __restrict__ cnt, const float* __restrict__ wg, u16* __restrict__ wgT,
    const float* __restrict__ wu, u16* __restrict__ wuT, const float* __restrict__ wd,
    u16* __restrict__ wdT) {
  __shared__ u16 t[2][64][72];  // 18,432 B -> 8 blocks/CU
  unsigned bid = blockIdx.x;
  if (bid < T_TOK / 4) {
    // ---- router + x->bf16 ----
    int wave = threadIdx.x >> 6;
    int lane = threadIdx.x & 63;
    int tok = bid * 4 + wave;
    float acc[NE];
#pragma unroll
    for (int e = 0; e < NE; ++e) acc[e] = 0.f;
    const float4* xr = (const float4*)(x + (size_t)tok * HDIM);
    u16* xbrow = xb + (size_t)tok * HDIM;
#pragma unroll
    for (int c = 0; c < HDIM / 256; ++c) {
      float4 xv = xr[c * 64 + lane];
      int h = (c * 64 + lane) * 4;
      ushort4 o = make_ushort4(f2bf(xv.x), f2bf(xv.y), f2bf(xv.z), f2bf(xv.w));
      *(ushort4*)(xbrow + h) = o;
      const float xs[4] = {xv.x, xv.y, xv.z, xv.w};
#pragma unroll
      for (int j = 0; j < 4; ++j) {
        const float* wrow = wgate + (size_t)(h + j) * NE;
#pragma unroll
        for (int e = 0; e < NE; ++e) acc[e] += xs[j] * wrow[e];
      }
    }
#pragma unroll
    for (int e = 0; e < NE; ++e) {
      float v = acc[e];
#pragma unroll
      for (int off = 32; off; off >>= 1) v += __shfl_xor(v, off, 64);
      acc[e] = v;
    }
    if (lane == 0) {
      float m = acc[0];
#pragma unroll
      for (int e = 0; e < NE; ++e) {
        logits_out[(size_t)tok * NE + e] = acc[e];
        m = fmaxf(m, acc[e]);
      }
      float p[NE];
#pragma unroll
      for (int e = 0; e < NE; ++e) p[e] = expf(acc[e] - m);
      int b0 = 0;
      float v0 = p[0];
#pragma unroll
      for (int e = 1; e < NE; ++e)
        if (p[e] > v0) { v0 = p[e]; b0 = e; }
      int b1 = -1;
      float v1 = -1.f;
#pragma unroll
      for (int e = 0; e < NE; ++e)
        if (e != b0 && p[e] > v1) { v1 = p[e]; b1 = e; }
      float denom = v0 + v1;
      sel[tok * 2 + 0] = (char)b0;
      sel[tok * 2 + 1] = (char)b1;
      wt[tok * 2 + 0] = v0 / denom;
      wt[tok * 2 + 1] = v1 / denom;
      atomicAdd(&cnt[b0], 1u);
      atomicAdd(&cnt[b1], 1u);
    }
    if (bid == 0 && threadIdx.x >= 8 && threadIdx.x < 16)
      cnt[threadIdx.x] = 0;  // cursor[8] (cnt itself memset'd before launch)
  } else {
    // ---- weight transpose+cvt: dst[n][k] = bf16(src[k][n]) ----
    unsigned tb = bid - T_TOK / 4;     // 0..6143
    unsigned mat = tb / 2048u;         // 0=wg 1=wu 2=wd
    unsigned rem = tb % 2048u;
    unsigned e = rem >> 8;             // /256
    unsigned tile = rem & 255u;
    int K = (mat == 2) ? IDIM : HDIM;
    int N = (mat == 2) ? HDIM : IDIM;
    const float* src = (mat == 0 ? wg : mat == 1 ? wu : wd) + (size_t)e * K * N;
    u16* dst = (mat == 0 ? wgT : mat == 1 ? wuT : wdT) + (size_t)e * K * N;
    int ntn = N >> 6;                        // n-tiles of 64
    int kb = (int)(tile / ntn) * 128;        // 128-k strip
    int nb = (int)(tile % ntn) * 64;

    int tid = threadIdx.x;
    int lk = tid >> 4, ln = (tid & 15) * 4;
    // all 8 loads upfront (2 sub-tiles x 4 rows)
    float4 v[2][4];
#pragma unroll
    for (int st = 0; st < 2; ++st)
#pragma unroll
      for (int p = 0; p < 4; ++p)
        v[st][p] = *(const float4*)(src + (size_t)(kb + st * 64 + lk + 16 * p) * N + nb + ln);
#pragma unroll
    for (int st = 0; st < 2; ++st)
#pragma unroll
      for (int p = 0; p < 4; ++p) {
        int k = lk + 16 * p;
        t[st][ln + 0][k] = f2bf(v[st][p].x);
        t[st][ln + 1][k] = f2bf(v[st][p].y);
        t[st][ln + 2][k] = f2bf(v[st][p].z);
        t[st][ln + 3][k] = f2bf(v[st][p].w);
      }
    __syncthreads();
    int n = tid >> 2, c16 = (tid & 3) * 16;
    u16* drow = dst + (size_t)(nb + n) * K + kb;
#pragma unroll
    for (int st = 0; st < 2; ++st) {
      short8 o0 = *(const short8*)&t[st][n][c16];
      short8 o1 = *(const short8*)&t[st][n][c16 + 8];
      *(short8*)(drow + st * 64 + c16) = o0;
      *(short8*)(drow + st * 64 + c16 + 8) = o1;
    }
  }
}

// ---------------- K3: slot assignment (local prefix) ----------------
__global__ __launch_bounds__(256) void k3_assign(const char* __restrict__ sel,
                                                 const float* __restrict__ wt,
                                                 const unsigned* __restrict__ cnt,
                                                 unsigned* __restrict__ cursor,
                                                 u16* __restrict__ slot_token,
                                                 float* __restrict__ slot_w,
                                                 u16* __restrict__ tok2slot) {
  unsigned offv[NE];
  unsigned s = 0;
#pragma unroll
  for (int e = 0; e < NE; ++e) {
    offv[e] = s;
    s += cnt[e];
  }
  int t = blockIdx.x * 256 + threadIdx.x;
#pragma unroll
  for (int k = 0; k < 2; ++k) {
    int e = sel[t * 2 + k];
    unsigned p = atomicAdd(&cursor[e], 1u);
    unsigned slot = offv[e] + p;
    slot_token[slot] = (u16)t;
    slot_w[slot] = wt[t * 2 + k];
    tok2slot[t * 2 + k] = (u16)slot;
  }
}

// Bijective XCD swizzle for 64x8x8 = 4096-block grids (8 XCDs, 512/XCD).
__device__ inline void xcd_decomp(int& bx, int& by, int& be) {
  unsigned bid = blockIdx.x + 64u * (blockIdx.y + 8u * blockIdx.z);
  unsigned swz = (bid & 7u) * 512u + (bid >> 3);
  bx = swz & 63u;
  unsigned rem = swz >> 6;
  by = rem & 7u;
  be = rem >> 3;
}

// local exclusive-prefix over cnt (8 uniform L2-hot loads)
__device__ inline unsigned prefix_base(const unsigned* cnt, int e) {
  unsigned b = 0;
#pragma unroll
  for (int i = 0; i < NE; ++i) b += (i < e) ? cnt[i] : 0u;
  return b;
}

// ---------------- K4: MFMA gate+up + silu -> bf16 act (R9/R13 structure) ----------------
// tile 128m x 128n (g+u), 4 waves, BK=32, ring-3 LDS (72 KB, 2 blocks/CU),
// depth-2 prefetch, counted vmcnt. Best-measured: ~221 us, MfmaUtil 27%.
__global__ __launch_bounds__(256, 2) void k4_gateup(
    const u16* __restrict__ xb, const u16* __restrict__ wgT, const u16* __restrict__ wuT,
    const u16* __restrict__ slot_token, const unsigned* __restrict__ cnt,
    u16* __restrict__ act) {
  int bx, by, e;
  xcd_decomp(bx, by, e);
  unsigned n = cnt[e];
  unsigned row0 = (unsigned)bx * 128;
  if (row0 >= n) return;
  unsigned base = prefix_base(cnt, e);
  int col0 = by * 128;

  __shared__ __align__(16) u16 As[3][128 * 32];  // 24 KB
  __shared__ __align__(16) u16 Bg[3][128 * 32];  // 24 KB
  __shared__ __align__(16) u16 Bu[3][128 * 32];  // 24 KB

  int tid = threadIdx.x;
  int w = tid >> 6, l = tid & 63;
  int wr = w >> 1, wc = w & 1;
  int lr = l & 15, g = l >> 4;

  const u16* asrc[2];
  int adst[2];
#pragma unroll
  for (int i = 0; i < 2; ++i) {
    int r = 32 * w + 16 * i + (l >> 2);
    unsigned grow = row0 + (unsigned)r;
    unsigned slot = base + (grow < n ? grow : 0);
    int chunk = (l & 3) ^ ((r >> 1) & 3);
    asrc[i] = xb + (size_t)slot_token[slot] * HDIM + 8 * chunk;
    adst[i] = (32 * w + 16 * i) * 32;
  }
  const u16* bgsrc[2];
  const u16* busrc[2];
  int bdst[2];
#pragma unroll
  for (int i = 0; i < 2; ++i) {
    int nn = 32 * w + 16 * i + (l >> 2);
    int chunk = (l & 3) ^ ((nn >> 1) & 3);
    size_t o = (size_t)e * HDIM * IDIM + (size_t)(col0 + nn) * HDIM + 8 * chunk;
    bgsrc[i] = wgT + o;
    busrc[i] = wuT + o;
    bdst[i] = (32 * w + 16 * i) * 32;
  }

  int afo[4], bfo[4];
#pragma unroll
  for (int mf = 0; mf < 4; ++mf) afo[mf] = rswz(wr * 64 + mf * 16 + lr, g);
#pragma unroll
  for (int nf = 0; nf < 4; ++nf) bfo[nf] = rswz(wc * 64 + nf * 16 + lr, g);

  f32x4 accg[4][4] = {};
  f32x4 accu[4][4] = {};

#define K4_STAGE(k0, buf)                           \
  do {                                              \
    gl_lds(asrc[0] + (k0), &As[buf][adst[0]]);      \
    gl_lds(asrc[1] + (k0), &As[buf][adst[1]]);      \
    gl_lds(bgsrc[0] + (k0), &Bg[buf][bdst[0]]);     \
    gl_lds(bgsrc[1] + (k0), &Bg[buf][bdst[1]]);     \
    gl_lds(busrc[0] + (k0), &Bu[buf][bdst[0]]);     \
    gl_lds(busrc[1] + (k0), &Bu[buf][bdst[1]]);     \
  } while (0)

  K4_STAGE(0, 0);
  K4_STAGE(32, 1);  // 12 loads in flight

  const int NK = HDIM / 32;
  int c = 0, sb = 2;
  for (int kt = 0; kt < NK; ++kt) {
    if (kt + 2 < NK) {
      K4_STAGE((kt + 2) * 32, sb);                       // 18 in flight
      asm volatile("s_waitcnt vmcnt(12)" ::: "memory");  // tile kt landed
    } else if (kt + 1 < NK) {
      asm volatile("s_waitcnt vmcnt(6)" ::: "memory");
    } else {
      asm volatile("s_waitcnt vmcnt(0)" ::: "memory");
    }
    __builtin_amdgcn_s_barrier();

    short8 af[4];
#pragma unroll
    for (int mf = 0; mf < 4; ++mf) af[mf] = *(const short8*)&As[c][afo[mf]];
#pragma unroll
    for (int nf = 0; nf < 4; ++nf) {
      short8 bgf = *(const short8*)&Bg[c][bfo[nf]];
      short8 buf = *(const short8*)&Bu[c][bfo[nf]];
#pragma unroll
      for (int mf = 0; mf < 4; ++mf) {
        accg[mf][nf] = __builtin_amdgcn_mfma_f32_16x16x32_bf16(af[mf], bgf, accg[mf][nf], 0, 0, 0);
        accu[mf][nf] = __builtin_amdgcn_mfma_f32_16x16x32_bf16(af[mf], buf, accu[mf][nf], 0, 0, 0);
      }
    }
    __builtin_amdgcn_s_barrier();
    c = (c == 2) ? 0 : c + 1;
    sb = (sb == 2) ? 0 : sb + 1;
  }
#undef K4_STAGE

  unsigned rows_left = n - row0;
#pragma unroll
  for (int mf = 0; mf < 4; ++mf)
#pragma unroll
    for (int nf = 0; nf < 4; ++nf)
#pragma unroll
      for (int j = 0; j < 4; ++j) {
        int rin = wr * 64 + mf * 16 + 4 * g + j;
        if ((unsigned)rin < rows_left) {
          size_t s = base + row0 + rin;
          int col = col0 + wc * 64 + nf * 16 + lr;
          float gg = accg[mf][nf][j];
          float uu = accu[mf][nf][j];
          float v = (gg / (1.f + expf(-gg))) * uu;
          act[s * IDIM + col] = f2bf(v);
        }
      }
}

// ---------------- K5: MFMA down -> bf16 y (R9/R13 structure) ----------------
// tile 128m x 256n, 4 waves (64x128 each), BK=32, ring-3, depth-2, counted vmcnt.
__global__ __launch_bounds__(256, 2) void k5_down(
    const u16* __restrict__ act, const u16* __restrict__ wdT,
    const unsigned* __restrict__ cnt, u16* __restrict__ y) {
  int bx, by, e;
  xcd_decomp(bx, by, e);
  unsigned n = cnt[e];
  unsigned row0 = (unsigned)bx * 128;
  if (row0 >= n) return;
  unsigned base = prefix_base(cnt, e);
  int col0 = by * 256;

  __shared__ __align__(16) u16 As[3][128 * 32];  // 24 KB
  __shared__ __align__(16) u16 Bs[3][256 * 32];  // 48 KB

  int tid = threadIdx.x;
  int w = tid >> 6, l = tid & 63;
  int wr = w >> 1, wc = w & 1;
  int lr = l & 15, g = l >> 4;

  const u16* asrc[2];
  int adst[2];
#pragma unroll
  for (int i = 0; i < 2; ++i) {
    int r = 32 * w + 16 * i + (l >> 2);
    unsigned grow = row0 + (unsigned)r;
    unsigned slot = base + (grow < n ? grow : 0);
    int chunk = (l & 3) ^ ((r >> 1) & 3);
    asrc[i] = act + (size_t)slot * IDIM + 8 * chunk;
    adst[i] = (32 * w + 16 * i) * 32;
  }
  const u16* bsrc[4];
  int bdst[4];
#pragma unroll
  for (int i = 0; i < 4; ++i) {
    int nn = 64 * w + 16 * i + (l >> 2);
    int chunk = (l & 3) ^ ((nn >> 1) & 3);
    bsrc[i] = wdT + (size_t)e * IDIM * HDIM + (size_t)(col0 + nn) * IDIM + 8 * chunk;
    bdst[i] = (64 * w + 16 * i) * 32;
  }

  int afo[4], bfo[8];
#pragma unroll
  for (int mf = 0; mf < 4; ++mf) afo[mf] = rswz(wr * 64 + mf * 16 + lr, g);
#pragma unroll
  for (int nf = 0; nf < 8; ++nf) bfo[nf] = rswz(wc * 128 + nf * 16 + lr, g);

  f32x4 acc[4][8] = {};

#define K5_STAGE(k0, buf)                        \
  do {                                           \
    gl_lds(asrc[0] + (k0), &As[buf][adst[0]]);   \
    gl_lds(asrc[1] + (k0), &As[buf][adst[1]]);   \
    gl_lds(bsrc[0] + (k0), &Bs[buf][bdst[0]]);   \
    gl_lds(bsrc[1] + (k0), &Bs[buf][bdst[1]]);   \
    gl_lds(bsrc[2] + (k0), &Bs[buf][bdst[2]]);   \
    gl_lds(bsrc[3] + (k0), &Bs[buf][bdst[3]]);   \
  } while (0)

  K5_STAGE(0, 0);
  K5_STAGE(32, 1);

  const int NK = IDIM / 32;
  int c = 0, sb = 2;
  for (int kt = 0; kt < NK; ++kt) {
    if (kt + 2 < NK) {
      K5_STAGE((kt + 2) * 32, sb);
      asm volatile("s_waitcnt vmcnt(12)" ::: "memory");
    } else if (kt + 1 < NK) {
      asm volatile("s_waitcnt vmcnt(6)" ::: "memory");
    } else {
      asm volatile("s_waitcnt vmcnt(0)" ::: "memory");
    }
    __builtin_amdgcn_s_barrier();

    short8 af[4];
#pragma unroll
    for (int mf = 0; mf < 4; ++mf) af[mf] = *(const short8*)&As[c][afo[mf]];
#pragma unroll
    for (int nf = 0; nf < 8; ++nf) {
      short8 bd = *(const short8*)&Bs[c][bfo[nf]];
#pragma unroll
      for (int mf = 0; mf < 4; ++mf)
        acc[mf][nf] = __builtin_amdgcn_mfma_f32_16x16x32_bf16(af[mf], bd, acc[mf][nf], 0, 0, 0);
    }
    __builtin_amdgcn_s_barrier();
    c = (c == 2) ? 0 : c + 1;
    sb = (sb == 2) ? 0 : sb + 1;
  }
#undef K5_STAGE

  unsigned rows_left = n - row0;
#pragma unroll
  for (int mf = 0; mf < 4; ++mf)
#pragma unroll
    for (int j = 0; j < 4; ++j) {
      int rin = wr * 64 + mf * 16 + 4 * g + j;
      if ((unsigned)rin < rows_left) {
        size_t s = base + row0 + rin;
        u16* yrow = y + s * HDIM + col0 + wc * 128 + lr;
#pragma unroll
        for (int nf = 0; nf < 8; ++nf) yrow[nf * 16] = f2bf(acc[mf][nf][j]);
      }
    }
}

// ---------------- K6: combine out[t] = w0*y[s0] + w1*y[s1] ----------------
__global__ __launch_bounds__(512) void k6_combine(const u16* __restrict__ y,
                                                  const u16* __restrict__ tok2slot,
                                                  const float* __restrict__ slot_w,
                                                  float* __restrict__ out) {
  unsigned idx = blockIdx.x * 512 + threadIdx.x;  // one per 8 elems
  int t = idx >> 8;                               // HDIM/8 = 256 chunks per row
  int off = (idx & 255) * 8;
  int s0 = tok2slot[t * 2 + 0];
  int s1 = tok2slot[t * 2 + 1];
  float w0 = slot_w[s0];
  float w1 = slot_w[s1];
  short8 a = *(const short8*)(y + (size_t)s0 * HDIM + off);
  short8 b = *(const short8*)(y + (size_t)s1 * HDIM + off);
  float* o = out + (size_t)t * HDIM + off;
  float4 o0, o1;
  o0.x = w0 * bf2f((u16)a[0]) + w1 * bf2f((u16)b[0]);
  o0.y = w0 * bf2f((u16)a[1]) + w1 * bf2f((u16)b[1]);
  o0.z = w0 * bf2f((u16)a[2]) + w1 * bf2f((u16)b[2]);
  o0.w = w0 * bf2f((u16)a[3]) + w1 * bf2f((u16)b[3]);
  o1.x = w0 * bf2f((u16)a[4]) + w1 * bf2f((u16)b[4]);
  o1.y = w0 * bf2f((u16)a[5]) + w1 * bf2f((u16)b[5]);
  o1.z = w0 * bf2f((u16)a[6]) + w1 * bf2f((u16)b[6]);
  o1.w = w0 * bf2f((u16)a[7]) + w1 * bf2f((u16)b[7]);
  *(float4*)o = o0;
  *(float4*)(o + 4) = o1;
}

extern "C" void kernel_launch(void* const* d_in, const int* in_sizes, int n_in,
                              void* d_out, int out_size, void* d_ws, size_t ws_size,
                              hipStream_t stream) {
  const float* x = (const float*)d_in[0];
  const float* wgate = (const float*)d_in[1];
  const float* wg = (const float*)d_in[2];
  const float* wu = (const float*)d_in[3];
  const float* wd = (const float*)d_in[4];
  float* out = (float*)d_out;
  float* logits = out + (size_t)T_TOK * HDIM;

  const size_t XBF_OFF = 132096;
  const size_t ACT_OFF = XBF_OFF + (size_t)T_TOK * HDIM * 2;
  const size_t WGT_OFF = ACT_OFF + (size_t)2 * T_TOK * IDIM * 2;
  const size_t WUT_OFF = WGT_OFF + (size_t)NE * HDIM * IDIM * 2;
  const size_t WDT_OFF = WUT_OFF + (size_t)NE * HDIM * IDIM * 2;
  const size_t NEED_T3 = WDT_OFF + (size_t)NE * IDIM * HDIM * 2;  // 167,904,256 (proven R5)
  if (ws_size < NEED_T3) return;  // loud failure

  char* ws = (char*)d_ws;
  unsigned* meta = (unsigned*)ws;
  unsigned* cnt = meta + 0;
  unsigned* cursor = meta + 8;
  u16* slot_token = (u16*)(ws + 256);
  float* slot_w = (float*)(ws + 33024);
  u16* tok2slot = (u16*)(ws + 98560);
  u16* xbf = (u16*)(ws + XBF_OFF);
  u16* act = (u16*)(ws + ACT_OFF);
  u16* wgT = (u16*)(ws + WGT_OFF);
  u16* wuT = (u16*)(ws + WUT_OFF);
  u16* wdT = (u16*)(ws + WDT_OFF);
  u16* y = (u16*)(ws + WGT_OFF);  // reuses wgT+wuT (dead after k4)
  char* sel = (char*)act;         // dead before k4 writes act
  float* wt = (float*)((char*)act + 16384);

  hipMemsetAsync(cnt, 0, 32, stream);
  k0t_fused<<<T_TOK / 4 + 3 * 2048, 256, 0, stream>>>(
      x, wgate, xbf, logits, sel, wt, cnt, wg, wgT, wu, wuT, wd, wdT);
  k3_assign<<<T_TOK / 256, 256, 0, stream>>>(sel, wt, cnt, cursor, slot_token, slot_w, tok2slot);
  k4_gateup<<<dim3(T_TOK / 128, IDIM / 128, NE), 256, 0, stream>>>(xbf, wgT, wuT, slot_token,
                                                                   cnt, act);
  k5_down<<<dim3(T_TOK / 128, HDIM / 256, NE), 256, 0, stream>>>(act, wdT, cnt, y);
  k6_combine<<<T_TOK * HDIM / 8 / 512, 512, 0, stream>>>(y, tok2slot, slot_w, out);
}

// Round 18
// 614.233 us; speedup vs baseline: 1.2702x; 1.0146x over previous
//
#include <hip/hip_runtime.h>
#include <math.h>

#define T_TOK 8192
#define HDIM 2048
#define IDIM 1024
#define NE 8

typedef __attribute__((ext_vector_type(8))) short short8;
typedef __attribute__((ext_vector_type(4))) float f32x4;
typedef unsigned short u16;

__device__ inline u16 f2bf(float f) {
  unsigned u = __builtin_bit_cast(unsigned, f);
  u += 0x7fffu + ((u >> 16) & 1);  // RNE
  return (u16)(u >> 16);
}
__device__ inline float bf2f(u16 u) {
  unsigned v = (unsigned)u << 16;
  return __builtin_bit_cast(float, v);
}

// async global->LDS, 16B/lane. LDS dest = wave-uniform base + lane*16.
__device__ inline void gl_lds(const u16* g, u16* l) {
  __builtin_amdgcn_global_load_lds((const __attribute__((address_space(1))) unsigned int*)g,
                                   (__attribute__((address_space(3))) unsigned int*)l, 16, 0, 0);
}

// bf16 LDS tiles [row][32] (64B rows); chunk swizzle applied on the GLOBAL
// source address (m173): position p holds global chunk p ^ ((row>>1)&3).
// Frag read of granule g: row*32 + 8*(g ^ ((row>>1)&3)) -> measured 0 conflicts.
__device__ inline int rswz(int row, int g) { return row * 32 + 8 * (g ^ ((row >> 1) & 3)); }

// ---------- ws layout ----------
// 0       meta: cnt[8] cursor[8] (u32)
// 256     slot_token u16[2T]  (32 KB)
// 33024   slot_w    f32[2T]   (64 KB)
// 98560   tok2slot  u16[2T]   (32 KB)   -> ends 131328
// 132096  xbf  bf16[T*H]      (33.5 MB)
// ACT     act  bf16[2T*I]     (33.5 MB)  (sel/wt stashed here pre-k4)
// WGT     wgT / wuT           (67 MB)    -> y bf16[2T*H] after k4 (exact fit)
// WDT     wdT                 (33.5 MB)  total 167,904,256 (proven R5)

// ---------------- K0T: FUSED router (blocks 0..2047) & transpose (2048..4095).
// Router: wgate slab staged in LDS per c-iter (coalesced; kills the 64-lane
// divergent gathers that serialized the L1 pipe). Transpose: 3 tiles/block,
// register-prefetch pipeline (compiler-managed waitcnts), 2 barriers/tile.
__global__ __launch_bounds__(256) void k0t_fused(
    const float* __restrict__ x, const float* __restrict__ wgate, u16* __restrict__ xb,
    float* __restrict__ logits_out, char* __restrict__ sel, float* __restrict__ wt,
    unsigned* __restrict__ cnt, const float* __restrict__ wg, u16* __restrict__ wgT,
    const float* __restrict__ wu, u16* __restrict__ wuT, const float* __restrict__ wd,
    u16* __restrict__ wdT) {
  __shared__ __align__(16) unsigned char smem[18432];
  unsigned bid = blockIdx.x;
  int tid = threadIdx.x;
  if (bid < T_TOK / 4) {
    // ---- router + x->bf16 (wgate via LDS slab) ----
    float* slab = (float*)smem;  // [256][9] f32, 9216 B
    int wave = tid >> 6;
    int lane = tid & 63;
    int tok = bid * 4 + wave;
    float acc[NE];
#pragma unroll
    for (int e = 0; e < NE; ++e) acc[e] = 0.f;
    const float4* xr = (const float4*)(x + (size_t)tok * HDIM);
    u16* xbrow = xb + (size_t)tok * HDIM;
    for (int c = 0; c < HDIM / 256; ++c) {
      if (c) __syncthreads();  // prev iter's slab reads done
      {
        const float4* wsrc = (const float4*)(wgate + (size_t)c * 2048 + tid * 8);
        float4 w0 = wsrc[0];
        float4 w1 = wsrc[1];
        float* sr = slab + tid * 9;
        sr[0] = w0.x; sr[1] = w0.y; sr[2] = w0.z; sr[3] = w0.w;
        sr[4] = w1.x; sr[5] = w1.y; sr[6] = w1.z; sr[7] = w1.w;
      }
      __syncthreads();
      float4 xv = xr[c * 64 + lane];
      int h = (c * 64 + lane) * 4;
      ushort4 o = make_ushort4(f2bf(xv.x), f2bf(xv.y), f2bf(xv.z), f2bf(xv.w));
      *(ushort4*)(xbrow + h) = o;
      const float xs[4] = {xv.x, xv.y, xv.z, xv.w};
#pragma unroll
      for (int j = 0; j < 4; ++j) {
        const float* wrow = slab + (size_t)(4 * lane + j) * 9;
#pragma unroll
        for (int e = 0; e < NE; ++e) acc[e] += xs[j] * wrow[e];
      }
    }
#pragma unroll
    for (int e = 0; e < NE; ++e) {
      float v = acc[e];
#pragma unroll
      for (int off = 32; off; off >>= 1) v += __shfl_xor(v, off, 64);
      acc[e] = v;
    }
    if (lane == 0) {
      float m = acc[0];
#pragma unroll
      for (int e = 0; e < NE; ++e) {
        logits_out[(size_t)tok * NE + e] = acc[e];
        m = fmaxf(m, acc[e]);
      }
      float p[NE];
#pragma unroll
      for (int e = 0; e < NE; ++e) p[e] = expf(acc[e] - m);
      int b0 = 0;
      float v0 = p[0];
#pragma unroll
      for (int e = 1; e < NE; ++e)
        if (p[e] > v0) { v0 = p[e]; b0 = e; }
      int b1 = -1;
      float v1 = -1.f;
#pragma unroll
      for (int e = 0; e < NE; ++e)
        if (e != b0 && p[e] > v1) { v1 = p[e]; b1 = e; }
      float denom = v0 + v1;
      sel[tok * 2 + 0] = (char)b0;
      sel[tok * 2 + 1] = (char)b1;
      wt[tok * 2 + 0] = v0 / denom;
      wt[tok * 2 + 1] = v1 / denom;
      atomicAdd(&cnt[b0], 1u);
      atomicAdd(&cnt[b1], 1u);
    }
    if (bid == 0 && tid >= 8 && tid < 16) cnt[tid] = 0;  // cursor[8]
  } else {
    // ---- transpose+cvt: dst[n][k] = bf16(src[k][n]); 3 tiles, pipelined ----
    typedef u16 (*tile_t)[64][72];
    tile_t t = (tile_t)smem;  // [2][64][72] u16 = 18,432 B
    unsigned tb = bid - T_TOK / 4;  // 0..2047
    const float* srcp[3];
    u16* dstp[3];
    int kb[3], nb[3], KK[3], NN[3];
#pragma unroll
    for (int i = 0; i < 3; ++i) {
      unsigned ti = 3 * tb + i;
      unsigned mat = ti / 2048u;  // 0=wg 1=wu 2=wd
      unsigned rem = ti % 2048u;
      unsigned e = rem >> 8;
      unsigned tile = rem & 255u;
      KK[i] = (mat == 2) ? IDIM : HDIM;
      NN[i] = (mat == 2) ? HDIM : IDIM;
      srcp[i] = (mat == 0 ? wg : mat == 1 ? wu : wd) + (size_t)e * KK[i] * NN[i];
      dstp[i] = (mat == 0 ? wgT : mat == 1 ? wuT : wdT) + (size_t)e * KK[i] * NN[i];
      int ntn = NN[i] >> 6;
      kb[i] = (int)(tile / ntn) * 128;
      nb[i] = (int)(tile % ntn) * 64;
    }
    int lk = tid >> 4, ln = (tid & 15) * 4;
    int nrow = tid >> 2, c16 = (tid & 3) * 16;

#define LOADT(vv, i)                                                                        \
  {                                                                                         \
    _Pragma("unroll") for (int st = 0; st < 2; ++st) _Pragma("unroll") for (int p = 0;      \
                                                                            p < 4; ++p)    \
        vv[st * 4 + p] = *(const float4*)(srcp[i] +                                         \
                                          (size_t)(kb[i] + st * 64 + lk + 16 * p) * NN[i] + \
                                          nb[i] + ln);                                      \
  }
#define LDSW(vv)                                          \
  {                                                       \
    _Pragma("unroll") for (int st = 0; st < 2; ++st)      \
        _Pragma("unroll") for (int p = 0; p < 4; ++p) {   \
      int k = lk + 16 * p;                                \
      t[st][ln + 0][k] = f2bf(vv[st * 4 + p].x);          \
      t[st][ln + 1][k] = f2bf(vv[st * 4 + p].y);          \
      t[st][ln + 2][k] = f2bf(vv[st * 4 + p].z);          \
      t[st][ln + 3][k] = f2bf(vv[st * 4 + p].w);          \
    }                                                     \
  }
#define WOUT(i)                                                          \
  {                                                                      \
    u16* drow = dstp[i] + (size_t)(nb[i] + nrow) * KK[i] + kb[i];        \
    _Pragma("unroll") for (int st = 0; st < 2; ++st) {                   \
      short8 o0 = *(const short8*)&t[st][nrow][c16];                     \
      short8 o1 = *(const short8*)&t[st][nrow][c16 + 8];                 \
      *(short8*)(drow + st * 64 + c16) = o0;                             \
      *(short8*)(drow + st * 64 + c16 + 8) = o1;                         \
    }                                                                    \
  }

    float4 va[8], vb[8];
    LOADT(va, 0);
    LOADT(vb, 1);
    // tile 0
    LDSW(va);          // compiler waits on va loads only (vb stays in flight)
    LOADT(va, 2);      // prefetch tile 2 (va regs free after LDSW consumed them)
    __syncthreads();
    WOUT(0);
    __syncthreads();   // tile-0 LDS reads done everywhere -> safe to overwrite
    // tile 1
    LDSW(vb);
    __syncthreads();
    WOUT(1);
    __syncthreads();
    // tile 2
    LDSW(va);
    __syncthreads();
    WOUT(2);
#undef LOADT
#undef LDSW
#undef WOUT
  }
}

// ---------------- K3: slot assignment (local prefix) ----------------
__global__ __launch_bounds__(256) void k3_assign(const char* __restrict__ sel,
                                                 const float* __restrict__ wt,
                                                 const unsigned* __restrict__ cnt,
                                                 unsigned* __restrict__ cursor,
                                                 u16* __restrict__ slot_token,
                                                 float* __restrict__ slot_w,
                                                 u16* __restrict__ tok2slot) {
  unsigned offv[NE];
  unsigned s = 0;
#pragma unroll
  for (int e = 0; e < NE; ++e) {
    offv[e] = s;
    s += cnt[e];
  }
  int t = blockIdx.x * 256 + threadIdx.x;
#pragma unroll
  for (int k = 0; k < 2; ++k) {
    int e = sel[t * 2 + k];
    unsigned p = atomicAdd(&cursor[e], 1u);
    unsigned slot = offv[e] + p;
    slot_token[slot] = (u16)t;
    slot_w[slot] = wt[t * 2 + k];
    tok2slot[t * 2 + k] = (u16)slot;
  }
}

// Bijective XCD swizzle for 64x8x8 = 4096-block grids (8 XCDs, 512/XCD).
__device__ inline void xcd_decomp(int& bx, int& by, int& be) {
  unsigned bid = blockIdx.x + 64u * (blockIdx.y + 8u * blockIdx.z);
  unsigned swz = (bid & 7u) * 512u + (bid >> 3);
  bx = swz & 63u;
  unsigned rem = swz >> 6;
  by = rem & 7u;
  be = rem >> 3;
}

// local exclusive-prefix over cnt (8 uniform L2-hot loads)
__device__ inline unsigned prefix_base(const unsigned* cnt, int e) {
  unsigned b = 0;
#pragma unroll
  for (int i = 0; i < NE; ++i) b += (i < e) ? cnt[i] : 0u;
  return b;
}

// ---------------- K4: MFMA gate+up + silu -> bf16 act (R9/R13 structure) ----------------
__global__ __launch_bounds__(256, 2) void k4_gateup(
    const u16* __restrict__ xb, const u16* __restrict__ wgT, const u16* __restrict__ wuT,
    const u16* __restrict__ slot_token, const unsigned* __restrict__ cnt,
    u16* __restrict__ act) {
  int bx, by, e;
  xcd_decomp(bx, by, e);
  unsigned n = cnt[e];
  unsigned row0 = (unsigned)bx * 128;
  if (row0 >= n) return;
  unsigned base = prefix_base(cnt, e);
  int col0 = by * 128;

  __shared__ __align__(16) u16 As[3][128 * 32];  // 24 KB
  __shared__ __align__(16) u16 Bg[3][128 * 32];  // 24 KB
  __shared__ __align__(16) u16 Bu[3][128 * 32];  // 24 KB

  int tid = threadIdx.x;
  int w = tid >> 6, l = tid & 63;
  int wr = w >> 1, wc = w & 1;
  int lr = l & 15, g = l >> 4;

  const u16* asrc[2];
  int adst[2];
#pragma unroll
  for (int i = 0; i < 2; ++i) {
    int r = 32 * w + 16 * i + (l >> 2);
    unsigned grow = row0 + (unsigned)r;
    unsigned slot = base + (grow < n ? grow : 0);
    int chunk = (l & 3) ^ ((r >> 1) & 3);
    asrc[i] = xb + (size_t)slot_token[slot] * HDIM + 8 * chunk;
    adst[i] = (32 * w + 16 * i) * 32;
  }
  const u16* bgsrc[2];
  const u16* busrc[2];
  int bdst[2];
#pragma unroll
  for (int i = 0; i < 2; ++i) {
    int nn = 32 * w + 16 * i + (l >> 2);
    int chunk = (l & 3) ^ ((nn >> 1) & 3);
    size_t o = (size_t)e * HDIM * IDIM + (size_t)(col0 + nn) * HDIM + 8 * chunk;
    bgsrc[i] = wgT + o;
    busrc[i] = wuT + o;
    bdst[i] = (32 * w + 16 * i) * 32;
  }

  int afo[4], bfo[4];
#pragma unroll
  for (int mf = 0; mf < 4; ++mf) afo[mf] = rswz(wr * 64 + mf * 16 + lr, g);
#pragma unroll
  for (int nf = 0; nf < 4; ++nf) bfo[nf] = rswz(wc * 64 + nf * 16 + lr, g);

  f32x4 accg[4][4] = {};
  f32x4 accu[4][4] = {};

#define K4_STAGE(k0, buf)                           \
  do {                                              \
    gl_lds(asrc[0] + (k0), &As[buf][adst[0]]);      \
    gl_lds(asrc[1] + (k0), &As[buf][adst[1]]);      \
    gl_lds(bgsrc[0] + (k0), &Bg[buf][bdst[0]]);     \
    gl_lds(bgsrc[1] + (k0), &Bg[buf][bdst[1]]);     \
    gl_lds(busrc[0] + (k0), &Bu[buf][bdst[0]]);     \
    gl_lds(busrc[1] + (k0), &Bu[buf][bdst[1]]);     \
  } while (0)

  K4_STAGE(0, 0);
  K4_STAGE(32, 1);  // 12 loads in flight

  const int NK = HDIM / 32;
  int c = 0, sb = 2;
  for (int kt = 0; kt < NK; ++kt) {
    if (kt + 2 < NK) {
      K4_STAGE((kt + 2) * 32, sb);                       // 18 in flight
      asm volatile("s_waitcnt vmcnt(12)" ::: "memory");  // tile kt landed
    } else if (kt + 1 < NK) {
      asm volatile("s_waitcnt vmcnt(6)" ::: "memory");
    } else {
      asm volatile("s_waitcnt vmcnt(0)" ::: "memory");
    }
    __builtin_amdgcn_s_barrier();

    short8 af[4];
#pragma unroll
    for (int mf = 0; mf < 4; ++mf) af[mf] = *(const short8*)&As[c][afo[mf]];
#pragma unroll
    for (int nf = 0; nf < 4; ++nf) {
      short8 bgf = *(const short8*)&Bg[c][bfo[nf]];
      short8 buf = *(const short8*)&Bu[c][bfo[nf]];
#pragma unroll
      for (int mf = 0; mf < 4; ++mf) {
        accg[mf][nf] = __builtin_amdgcn_mfma_f32_16x16x32_bf16(af[mf], bgf, accg[mf][nf], 0, 0, 0);
        accu[mf][nf] = __builtin_amdgcn_mfma_f32_16x16x32_bf16(af[mf], buf, accu[mf][nf], 0, 0, 0);
      }
    }
    __builtin_amdgcn_s_barrier();
    c = (c == 2) ? 0 : c + 1;
    sb = (sb == 2) ? 0 : sb + 1;
  }
#undef K4_STAGE

  unsigned rows_left = n - row0;
#pragma unroll
  for (int mf = 0; mf < 4; ++mf)
#pragma unroll
    for (int nf = 0; nf < 4; ++nf)
#pragma unroll
      for (int j = 0; j < 4; ++j) {
        int rin = wr * 64 + mf * 16 + 4 * g + j;
        if ((unsigned)rin < rows_left) {
          size_t s = base + row0 + rin;
          int col = col0 + wc * 64 + nf * 16 + lr;
          float gg = accg[mf][nf][j];
          float uu = accu[mf][nf][j];
          float v = (gg / (1.f + expf(-gg))) * uu;
          act[s * IDIM + col] = f2bf(v);
        }
      }
}

// ---------------- K5: MFMA down -> bf16 y (R9/R13 structure) ----------------
__global__ __launch_bounds__(256, 2) void k5_down(
    const u16* __restrict__ act, const u16* __restrict__ wdT,
    const unsigned* __restrict__ cnt, u16* __restrict__ y) {
  int bx, by, e;
  xcd_decomp(bx, by, e);
  unsigned n = cnt[e];
  unsigned row0 = (unsigned)bx * 128;
  if (row0 >= n) return;
  unsigned base = prefix_base(cnt, e);
  int col0 = by * 256;

  __shared__ __align__(16) u16 As[3][128 * 32];  // 24 KB
  __shared__ __align__(16) u16 Bs[3][256 * 32];  // 48 KB

  int tid = threadIdx.x;
  int w = tid >> 6, l = tid & 63;
  int wr = w >> 1, wc = w & 1;
  int lr = l & 15, g = l >> 4;

  const u16* asrc[2];
  int adst[2];
#pragma unroll
  for (int i = 0; i < 2; ++i) {
    int r = 32 * w + 16 * i + (l >> 2);
    unsigned grow = row0 + (unsigned)r;
    unsigned slot = base + (grow < n ? grow : 0);
    int chunk = (l & 3) ^ ((r >> 1) & 3);
    asrc[i] = act + (size_t)slot * IDIM + 8 * chunk;
    adst[i] = (32 * w + 16 * i) * 32;
  }
  const u16* bsrc[4];
  int bdst[4];
#pragma unroll
  for (int i = 0; i < 4; ++i) {
    int nn = 64 * w + 16 * i + (l >> 2);
    int chunk = (l & 3) ^ ((nn >> 1) & 3);
    bsrc[i] = wdT + (size_t)e * IDIM * HDIM + (size_t)(col0 + nn) * IDIM + 8 * chunk;
    bdst[i] = (64 * w + 16 * i) * 32;
  }

  int afo[4], bfo[8];
#pragma unroll
  for (int mf = 0; mf < 4; ++mf) afo[mf] = rswz(wr * 64 + mf * 16 + lr, g);
#pragma unroll
  for (int nf = 0; nf < 8; ++nf) bfo[nf] = rswz(wc * 128 + nf * 16 + lr, g);

  f32x4 acc[4][8] = {};

#define K5_STAGE(k0, buf)                        \
  do {                                           \
    gl_lds(asrc[0] + (k0), &As[buf][adst[0]]);   \
    gl_lds(asrc[1] + (k0), &As[buf][adst[1]]);   \
    gl_lds(bsrc[0] + (k0), &Bs[buf][bdst[0]]);   \
    gl_lds(bsrc[1] + (k0), &Bs[buf][bdst[1]]);   \
    gl_lds(bsrc[2] + (k0), &Bs[buf][bdst[2]]);   \
    gl_lds(bsrc[3] + (k0), &Bs[buf][bdst[3]]);   \
  } while (0)

  K5_STAGE(0, 0);
  K5_STAGE(32, 1);

  const int NK = IDIM / 32;
  int c = 0, sb = 2;
  for (int kt = 0; kt < NK; ++kt) {
    if (kt + 2 < NK) {
      K5_STAGE((kt + 2) * 32, sb);
      asm volatile("s_waitcnt vmcnt(12)" ::: "memory");
    } else if (kt + 1 < NK) {
      asm volatile("s_waitcnt vmcnt(6)" ::: "memory");
    } else {
      asm volatile("s_waitcnt vmcnt(0)" ::: "memory");
    }
    __builtin_amdgcn_s_barrier();

    short8 af[4];
#pragma unroll
    for (int mf = 0; mf < 4; ++mf) af[mf] = *(const short8*)&As[c][afo[mf]];
#pragma unroll
    for (int nf = 0; nf < 8; ++nf) {
      short8 bd = *(const short8*)&Bs[c][bfo[nf]];
#pragma unroll
      for (int mf = 0; mf < 4; ++mf)
        acc[mf][nf] = __builtin_amdgcn_mfma_f32_16x16x32_bf16(af[mf], bd, acc[mf][nf], 0, 0, 0);
    }
    __builtin_amdgcn_s_barrier();
    c = (c == 2) ? 0 : c + 1;
    sb = (sb == 2) ? 0 : sb + 1;
  }
#undef K5_STAGE

  unsigned rows_left = n - row0;
#pragma unroll
  for (int mf = 0; mf < 4; ++mf)
#pragma unroll
    for (int j = 0; j < 4; ++j) {
      int rin = wr * 64 + mf * 16 + 4 * g + j;
      if ((unsigned)rin < rows_left) {
        size_t s = base + row0 + rin;
        u16* yrow = y + s * HDIM + col0 + wc * 128 + lr;
#pragma unroll
        for (int nf = 0; nf < 8; ++nf) yrow[nf * 16] = f2bf(acc[mf][nf][j]);
      }
    }
}

// ---------------- K6: combine out[t] = w0*y[s0] + w1*y[s1] ----------------
__global__ __launch_bounds__(512) void k6_combine(const u16* __restrict__ y,
                                                  const u16* __restrict__ tok2slot,
                                                  const float* __restrict__ slot_w,
                                                  float* __restrict__ out) {
  unsigned idx = blockIdx.x * 512 + threadIdx.x;  // one per 8 elems
  int t = idx >> 8;                               // HDIM/8 = 256 chunks per row
  int off = (idx & 255) * 8;
  int s0 = tok2slot[t * 2 + 0];
  int s1 = tok2slot[t * 2 + 1];
  float w0 = slot_w[s0];
  float w1 = slot_w[s1];
  short8 a = *(const short8*)(y + (size_t)s0 * HDIM + off);
  short8 b = *(const short8*)(y + (size_t)s1 * HDIM + off);
  float* o = out + (size_t)t * HDIM + off;
  float4 o0, o1;
  o0.x = w0 * bf2f((u16)a[0]) + w1 * bf2f((u16)b[0]);
  o0.y = w0 * bf2f((u16)a[1]) + w1 * bf2f((u16)b[1]);
  o0.z = w0 * bf2f((u16)a[2]) + w1 * bf2f((u16)b[2]);
  o0.w = w0 * bf2f((u16)a[3]) + w1 * bf2f((u16)b[3]);
  o1.x = w0 * bf2f((u16)a[4]) + w1 * bf2f((u16)b[4]);
  o1.y = w0 * bf2f((u16)a[5]) + w1 * bf2f((u16)b[5]);
  o1.z = w0 * bf2f((u16)a[6]) + w1 * bf2f((u16)b[6]);
  o1.w = w0 * bf2f((u16)a[7]) + w1 * bf2f((u16)b[7]);
  *(float4*)o = o0;
  *(float4*)(o + 4) = o1;
}

extern "C" void kernel_launch(void* const* d_in, const int* in_sizes, int n_in,
                              void* d_out, int out_size, void* d_ws, size_t ws_size,
                              hipStream_t stream) {
  const float* x = (const float*)d_in[0];
  const float* wgate = (const float*)d_in[1];
  const float* wg = (const float*)d_in[2];
  const float* wu = (const float*)d_in[3];
  const float* wd = (const float*)d_in[4];
  float* out = (float*)d_out;
  float* logits = out + (size_t)T_TOK * HDIM;

  const size_t XBF_OFF = 132096;
  const size_t ACT_OFF = XBF_OFF + (size_t)T_TOK * HDIM * 2;
  const size_t WGT_OFF = ACT_OFF + (size_t)2 * T_TOK * IDIM * 2;
  const size_t WUT_OFF = WGT_OFF + (size_t)NE * HDIM * IDIM * 2;
  const size_t WDT_OFF = WUT_OFF + (size_t)NE * HDIM * IDIM * 2;
  const size_t NEED_T3 = WDT_OFF + (size_t)NE * IDIM * HDIM * 2;  // 167,904,256 (proven R5)
  if (ws_size < NEED_T3) return;  // loud failure

  char* ws = (char*)d_ws;
  unsigned* meta = (unsigned*)ws;
  unsigned* cnt = meta + 0;
  unsigned* cursor = meta + 8;
  u16* slot_token = (u16*)(ws + 256);
  float* slot_w = (float*)(ws + 33024);
  u16* tok2slot = (u16*)(ws + 98560);
  u16* xbf = (u16*)(ws + XBF_OFF);
  u16* act = (u16*)(ws + ACT_OFF);
  u16* wgT = (u16*)(ws + WGT_OFF);
  u16* wuT = (u16*)(ws + WUT_OFF);
  u16* wdT = (u16*)(ws + WDT_OFF);
  u16* y = (u16*)(ws + WGT_OFF);  // reuses wgT+wuT (dead after k4)
  char* sel = (char*)act;         // dead before k4 writes act
  float* wt = (float*)((char*)act + 16384);

  hipMemsetAsync(cnt, 0, 32, stream);
  k0t_fused<<<T_TOK / 4 + 2048, 256, 0, stream>>>(
      x, wgate, xbf, logits, sel, wt, cnt, wg, wgT, wu, wuT, wd, wdT);
  k3_assign<<<T_TOK / 256, 256, 0, stream>>>(sel, wt, cnt, cursor, slot_token, slot_w, tok2slot);
  k4_gateup<<<dim3(T_TOK / 128, IDIM / 128, NE), 256, 0, stream>>>(xbf, wgT, wuT, slot_token,
                                                                   cnt, act);
  k5_down<<<dim3(T_TOK / 128, HDIM / 256, NE), 256, 0, stream>>>(act, wdT, cnt, y);
  k6_combine<<<T_TOK * HDIM / 8 / 512, 512, 0, stream>>>(y, tok2slot, slot_w, out);
}